// Round 1
// 1938.865 us; speedup vs baseline: 1.0305x; 1.0305x over previous
//
#include <hip/hip_runtime.h>
#include <math.h>

#define DEV __device__ __forceinline__
#define LSTRIDE 8537088

DEV float gelu_exact(float x){ return 0.5f*x*(1.0f+erff(x*0.70710678118654752440f)); }

DEV unsigned short f2bf(float x){
  union { float f; unsigned int u; } v; v.f = x;
  unsigned int r = v.u + 0x7FFFu + ((v.u >> 16) & 1u);
  return (unsigned short)(r >> 16);
}
DEV float bf2f(unsigned short b){ union { unsigned int u; float f; } v; v.u = ((unsigned int)b)<<16; return v.f; }
DEV void split2(float x, unsigned short& h, unsigned short& l){
  h = f2bf(x); l = f2bf(x - bf2f(h));
}

typedef __bf16 bf16x8 __attribute__((ext_vector_type(8)));
typedef float  f32x4  __attribute__((ext_vector_type(4)));

DEV void gload16(const void* g, void* lds){
  __builtin_amdgcn_global_load_lds((const __attribute__((address_space(1))) unsigned int*)g,
                                   (__attribute__((address_space(3))) unsigned int*)lds, 16, 0, 0);
}

// ======================= Fourier-encode data grid =======================
__global__ __launch_bounds__(256) void k_encode(float* __restrict__ data)
{
  int p = blockIdx.x*256 + threadIdx.x;
  int hh = p >> 7, ww = p & 127;
  float y = -1.0f + hh*(2.0f/127.0f);
  float x = -1.0f + ww*(2.0f/127.0f);
  float e[26];
  #pragma unroll
  for (int i=0;i<6;i++){
    float sc = exp2f(1.0f + i*0.26438561897747245f) * 3.14159265358979323846f;
    e[i]     = sinf(y*sc);
    e[6+i]   = cosf(y*sc);
    e[13+i]  = sinf(x*sc);
    e[19+i]  = cosf(x*sc);
  }
  e[12]=y; e[25]=x;
  #pragma unroll
  for (int b=0;b<8;b++){
    float* dr = data + ((size_t)(b*16384 + p))*29;
    dr[0]=0.f; dr[1]=0.f; dr[2]=0.f;
    #pragma unroll
    for (int c=0;c<26;c++) dr[3+c]=e[c];
  }
}

// ======================= lat = x @ W_l2l + b + latents =======================
__global__ __launch_bounds__(256) void k_l2l(const float* __restrict__ x,
    const float* __restrict__ Wl, const float* __restrict__ bl,
    const float* __restrict__ latents, float* __restrict__ lat)
{
  __shared__ float xs[8*512];
  int tid = threadIdx.x;
  for (int idx=tid; idx<4096; idx+=256) xs[idx]=x[idx];
  __syncthreads();
  int nIdx = blockIdx.x*256 + tid;
  float acc[8] = {0,0,0,0,0,0,0,0};
  for (int k=0;k<512;k++){
    float w = Wl[(size_t)k*131072 + nIdx];
    #pragma unroll
    for (int m=0;m<8;m++) acc[m] += xs[m*512+k]*w;
  }
  float add = bl[nIdx] + latents[nIdx];
  #pragma unroll
  for (int m=0;m<8;m++) lat[(size_t)m*131072 + nIdx] = acc[m] + add;
}

// ======================= LayerNorm D=512 -> split bf16 hi/lo =======================
__global__ __launch_bounds__(256) void k_ln512s(const float* __restrict__ X,
    const float* __restrict__ g, const float* __restrict__ bv,
    unsigned short* __restrict__ hi, unsigned short* __restrict__ lo)
{
  __shared__ float red[8];
  int row = blockIdx.x, tid = threadIdx.x;
  const float* x = X + (size_t)row*512;
  float v0 = x[tid], v1 = x[tid+256];
  float s = v0+v1;
  #pragma unroll
  for (int off=32; off; off>>=1) s += __shfl_xor(s, off);
  if ((tid&63)==0) red[tid>>6] = s;
  __syncthreads();
  float mean = (red[0]+red[1]+red[2]+red[3]) * (1.0f/512.0f);
  float d0 = v0-mean, d1 = v1-mean;
  float q = d0*d0 + d1*d1;
  #pragma unroll
  for (int off=32; off; off>>=1) q += __shfl_xor(q, off);
  if ((tid&63)==0) red[4+(tid>>6)] = q;
  __syncthreads();
  float var = (red[4]+red[5]+red[6]+red[7]) * (1.0f/512.0f);
  float rstd = rsqrtf(var + 1e-5f);
  float y0 = d0*rstd*g[tid]     + bv[tid];
  float y1 = d1*rstd*g[tid+256] + bv[tid+256];
  unsigned short h,l;
  split2(y0,h,l); hi[(size_t)row*512+tid]=h;     lo[(size_t)row*512+tid]=l;
  split2(y1,h,l); hi[(size_t)row*512+tid+256]=h; lo[(size_t)row*512+tid+256]=l;
}

// ======================= weight split+transpose, batched over layers (z) ==========
// W(KxN) layer stride K*N -> Wt hi|lo (NxK) at hi + z*LSTRIDE
__global__ __launch_bounds__(256) void k_split_w(const float* __restrict__ W,
    unsigned short* __restrict__ hi, int K, int N)
{
  __shared__ float t[64][65];
  int z = blockIdx.z;
  W  += (size_t)z*K*N;
  hi += (size_t)z*LSTRIDE;
  unsigned short* lo = hi + (size_t)N*K;
  int k0 = blockIdx.x*64, n0 = blockIdx.y*64;
  int tid = threadIdx.x;
  #pragma unroll
  for (int i=0;i<4;i++){
    int s = tid + 256*i;
    int r = s >> 4, c4 = (s & 15)*4;
    float4 v = *(const float4*)&W[(size_t)(k0+r)*N + n0 + c4];
    t[r][c4+0]=v.x; t[r][c4+1]=v.y; t[r][c4+2]=v.z; t[r][c4+3]=v.w;
  }
  __syncthreads();
  #pragma unroll
  for (int i=0;i<4;i++){
    int s = tid + 256*i;
    int n = s >> 4, kc = (s & 15)*4;
    size_t o = (size_t)(n0+n)*K + k0 + kc;
    #pragma unroll
    for (int j=0;j<4;j++){
      unsigned short h,l; split2(t[kc+j][n], h, l);
      hi[o+j]=h; lo[o+j]=l;
    }
  }
}

// ======================= generic small transpose, batched over layers (z) =========
__global__ __launch_bounds__(256) void k_prep_t(const float* __restrict__ src,
    unsigned short* __restrict__ dst, int K, int N, int Kd, int Nd)
{
  int z = blockIdx.z;
  src += (size_t)z*K*N;
  dst += (size_t)z*LSTRIDE;
  for (int idx = blockIdx.x*256 + threadIdx.x; idx < Nd*Kd; idx += gridDim.x*256){
    int n = idx / Kd, k = idx - n*Kd;
    float v = (k<K && n<N) ? src[(size_t)k*N + n] : 0.f;
    dst[idx] = f2bf(v);
  }
}

// ======================= W1 reorder+transpose (batched): (29x232)->(256x32), b1->b1r
__global__ __launch_bounds__(256) void k_prep_w1(const float* __restrict__ W1,
    const float* __restrict__ b1, unsigned short* __restrict__ dst)
{
  int z = blockIdx.z;
  W1  += (size_t)z*6728;
  b1  += (size_t)z*232;
  dst += (size_t)z*LSTRIDE;
  float* b1r = (float*)(dst + 8192);
  for (int idx = blockIdx.x*256 + threadIdx.x; idx < 256*32; idx += gridDim.x*256){
    int n = idx >> 5, k = idx & 31;
    int f = n & 127, isg = n >> 7;
    float v = 0.f;
    if (f < 116 && k < 29) v = W1[(size_t)k*232 + isg*116 + f];
    dst[idx] = f2bf(v);
  }
  int n = blockIdx.x*256 + threadIdx.x;
  if (n < 256){
    int f = n & 127, isg = n >> 7;
    b1r[n] = (f < 116) ? b1[isg*116 + f] : 0.f;
  }
}

// ======================= split-bf16 MFMA GEMM (latent path) =============
// accum==0 && gridDim.z>1: each z writes its partial to C + z*M*N (summed downstream)
__global__ __launch_bounds__(256) void k_mfma(
    const unsigned short* __restrict__ Ahi, const unsigned short* __restrict__ Bhi,
    const float* __restrict__ bias, float* __restrict__ C,
    int M, int N, int K, int Ksplit, int accum)
{
  __shared__ unsigned short sm[4*128*32];
  int tid = threadIdx.x, lane = tid & 63, w = tid >> 6;
  int bm = blockIdx.x*128, bn = blockIdx.y*128;
  int Ks = K / Ksplit;
  int kbeg = blockIdx.z * Ks;
  const unsigned short* tsrc;
  if      (w==0) tsrc = Ahi + (size_t)bm*K;
  else if (w==1) tsrc = Ahi + (size_t)M*K + (size_t)bm*K;
  else if (w==2) tsrc = Bhi + (size_t)bn*K;
  else           tsrc = Bhi + (size_t)N*K + (size_t)bn*K;
  unsigned short* mylds = sm + w*4096;
  f32x4 acc[4][4];
  #pragma unroll
  for(int i=0;i<4;i++)
    #pragma unroll
    for(int j=0;j<4;j++) acc[i][j] = (f32x4){0.f,0.f,0.f,0.f};
  int wm = (w>>1)*64, wn = (w&1)*64;
  int frow = lane & 15, fq = lane >> 4;
  for (int k0 = kbeg; k0 < kbeg + Ks; k0 += 32){
    #pragma unroll
    for (int j=0;j<8;j++){
      int idx = j*64 + lane;
      int row = idx >> 2, qp = idx & 3;
      int q = (qp - row) & 3;
      gload16(tsrc + (size_t)row*K + k0 + q*8, mylds + j*512);
    }
    __syncthreads();
    bf16x8 ah[4], al[4];
    #pragma unroll
    for (int mt=0;mt<4;mt++){
      int row = wm + mt*16 + frow;
      int off = row*32 + ((fq + row)&3)*8;
      ah[mt] = *(const bf16x8*)(sm + off);
      al[mt] = *(const bf16x8*)(sm + 4096 + off);
    }
    #pragma unroll
    for (int nt=0;nt<4;nt++){
      int rowb = wn + nt*16 + frow;
      int offb = rowb*32 + ((fq + rowb)&3)*8;
      bf16x8 bh = *(const bf16x8*)(sm + 2*4096 + offb);
      bf16x8 bl = *(const bf16x8*)(sm + 3*4096 + offb);
      #pragma unroll
      for (int mt=0;mt<4;mt++){
        acc[mt][nt] = __builtin_amdgcn_mfma_f32_16x16x32_bf16(ah[mt], bh, acc[mt][nt], 0,0,0);
        acc[mt][nt] = __builtin_amdgcn_mfma_f32_16x16x32_bf16(ah[mt], bl, acc[mt][nt], 0,0,0);
        acc[mt][nt] = __builtin_amdgcn_mfma_f32_16x16x32_bf16(al[mt], bh, acc[mt][nt], 0,0,0);
      }
    }
    __syncthreads();
  }
  size_t zoff = (size_t)blockIdx.z * ((size_t)M*N);
  #pragma unroll
  for (int mt=0;mt<4;mt++){
    #pragma unroll
    for (int nt=0;nt<4;nt++){
      int col = bn + wn + nt*16 + frow;
      float bv = (bias && blockIdx.z==0) ? bias[col] : 0.f;
      #pragma unroll
      for (int r=0;r<4;r++){
        int row = bm + wm + mt*16 + fq*4 + r;
        float v = acc[mt][nt][r] + bv;
        if (accum) atomicAdd(&C[(size_t)row*N + col], v);
        else       C[zoff + (size_t)row*N + col] = v;
      }
    }
  }
}

// ======================= fused latent FF1 + GEGLU (split-bf16 in, split-bf16 out) ===
// block: 128 rows x (64 a-cols + matching 64 g-cols). W rows: [bnp,bnp+64) a, [2048+bnp,..) g
__global__ __launch_bounds__(256) void k_mfma_glu(
    const unsigned short* __restrict__ Ahi, const unsigned short* __restrict__ Whi,
    const float* __restrict__ b1, unsigned short* __restrict__ Ghi,
    unsigned short* __restrict__ Glo)
{
  __shared__ unsigned short sm[16384];   // chunks: A_h[512] A_l[512] Ba_h[256] Bg_h[256] Ba_l[256] Bg_l[256]
  int tid = threadIdx.x, lane = tid & 63, w = tid >> 6;
  int bm = blockIdx.x*128, bnp = blockIdx.y*64;
  const unsigned short* Alo = Ahi + (size_t)2048*512;
  const unsigned short* Wlo = Whi + (size_t)4096*512;
  f32x4 aa[4][2], ag[4][2];
  #pragma unroll
  for (int i=0;i<4;i++)
    #pragma unroll
    for (int j=0;j<2;j++){ aa[i][j]=(f32x4){0.f,0.f,0.f,0.f}; ag[i][j]=(f32x4){0.f,0.f,0.f,0.f}; }
  int wm = (w>>1)*64, wnp = (w&1)*32;
  int frow = lane & 15, fq = lane >> 4;
  for (int k0=0;k0<512;k0+=32){
    #pragma unroll
    for (int j=0;j<8;j++){
      int c0 = w*512 + j*64;            // wave-uniform, 64-chunk aligned -> buf uniform
      int c  = c0 + lane;
      int sel = c0 >> 8;                // 0..7
      const unsigned short* src; int wi;
      if (sel < 4){                     // A hi (0,1) / A lo (2,3), 128 rows
        src = (sel < 2 ? Ahi : Alo) + (size_t)bm*512;
        wi = c & 511;
      } else {                          // B: 4=Ba_h 5=Bg_h 6=Ba_l 7=Bg_l, 64 rows each
        const unsigned short* wb = (sel < 6) ? Whi : Wlo;
        int cb = bnp + ((sel & 1) ? 2048 : 0);
        src = wb + (size_t)cb*512;
        wi = c & 255;
      }
      int row = wi >> 2, qp = wi & 3;
      int q = (qp - row) & 3;
      gload16(src + (size_t)row*512 + k0 + q*8, sm + c0*8);
    }
    __syncthreads();
    bf16x8 ah[4], al[4];
    #pragma unroll
    for (int mt=0;mt<4;mt++){
      int r = wm + mt*16 + frow;
      int off = r*32 + ((fq + r)&3)*8;
      ah[mt] = *(const bf16x8*)(sm + off);
      al[mt] = *(const bf16x8*)(sm + 4096 + off);
    }
    #pragma unroll
    for (int nt=0;nt<2;nt++){
      int rb = wnp + nt*16 + frow;
      int offb = rb*32 + ((fq + rb)&3)*8;
      bf16x8 bah = *(const bf16x8*)(sm +  8192 + offb);
      bf16x8 bgh = *(const bf16x8*)(sm + 10240 + offb);
      bf16x8 bal = *(const bf16x8*)(sm + 12288 + offb);
      bf16x8 bgl = *(const bf16x8*)(sm + 14336 + offb);
      #pragma unroll
      for (int mt=0;mt<4;mt++){
        aa[mt][nt] = __builtin_amdgcn_mfma_f32_16x16x32_bf16(ah[mt], bah, aa[mt][nt], 0,0,0);
        aa[mt][nt] = __builtin_amdgcn_mfma_f32_16x16x32_bf16(ah[mt], bal, aa[mt][nt], 0,0,0);
        aa[mt][nt] = __builtin_amdgcn_mfma_f32_16x16x32_bf16(al[mt], bah, aa[mt][nt], 0,0,0);
        ag[mt][nt] = __builtin_amdgcn_mfma_f32_16x16x32_bf16(ah[mt], bgh, ag[mt][nt], 0,0,0);
        ag[mt][nt] = __builtin_amdgcn_mfma_f32_16x16x32_bf16(ah[mt], bgl, ag[mt][nt], 0,0,0);
        ag[mt][nt] = __builtin_amdgcn_mfma_f32_16x16x32_bf16(al[mt], bgh, ag[mt][nt], 0,0,0);
      }
    }
    __syncthreads();
  }
  #pragma unroll
  for (int mt=0;mt<4;mt++){
    #pragma unroll
    for (int nt=0;nt<2;nt++){
      int col = bnp + wnp + nt*16 + frow;
      float ba = b1[col], bg = b1[2048+col];
      #pragma unroll
      for (int r=0;r<4;r++){
        int row = bm + wm + mt*16 + fq*4 + r;
        float av = aa[mt][nt][r] + ba;
        float gv = ag[mt][nt][r] + bg;
        unsigned short h,l; split2(av*gelu_exact(gv), h, l);
        Ghi[(size_t)row*2048 + col] = h;
        Glo[(size_t)row*2048 + col] = l;
      }
    }
  }
}

// ======================= KV prep: kv fp32 (z-partials summed) -> Kb bf16 / Vt =======
__global__ __launch_bounds__(256) void k_kvprep(const float* __restrict__ kv, int ld,
    int koff, int voff, int heads, int BH,
    unsigned short* __restrict__ Kb, unsigned short* __restrict__ Vthi,
    unsigned short* __restrict__ Vtlo, int zparts, int zstride)
{
  int total = BH << 14;
  for (int idx = blockIdx.x*256 + threadIdx.x; idx < total; idx += gridDim.x*256){
    int d = idx & 63, j = (idx>>6) & 255, bh = idx >> 14;
    int b = bh / heads, h = bh - b*heads;
    size_t base = ((size_t)(b*256 + j))*ld + koff + h*64 + d;
    float v = 0.f;
    for (int z=0; z<zparts; z++) v += kv[(size_t)z*zstride + base];
    Kb[idx] = f2bf(v);
  }
  for (int idx = blockIdx.x*256 + threadIdx.x; idx < total; idx += gridDim.x*256){
    int j = idx & 255, d = (idx>>8) & 63, bh = idx >> 14;
    int b = bh / heads, h = bh - b*heads;
    size_t base = ((size_t)(b*256 + j))*ld + voff + h*64 + d;
    float v = 0.f;
    for (int z=0; z<zparts; z++) v += kv[(size_t)z*zstride + base];
    if (Vtlo){ unsigned short hh,ll; split2(v,hh,ll); Vthi[idx]=hh; Vtlo[idx]=ll; }
    else Vthi[idx] = f2bf(v);
  }
}

// ======================= MFMA attention: 16 queries/wave, 256 keys, dh=64 ==========
template<int QF32, int SPLITV, int OSPLIT>
__global__ __launch_bounds__(256) void k_attn_mf(
    const void* __restrict__ Qv, const unsigned short* __restrict__ Kb,
    const unsigned short* __restrict__ Vthi, const unsigned short* __restrict__ Vtlo,
    unsigned short* __restrict__ O0, unsigned short* __restrict__ O1,
    int q_rs, int o_rs, int heads, int nper, float scale)
{
  __shared__ unsigned short Pw[4*640];
  int tid = threadIdx.x, lane = tid & 63, w = tid >> 6;
  int l15 = lane & 15, g = lane >> 4;
  int bpb = nper >> 6;
  int bh = blockIdx.x / bpb;
  int q0 = (blockIdx.x - bh*bpb)*64 + w*16;
  int b = bh / heads, h = bh - b*heads;
  bf16x8 aq[2];
  int qrow = b*nper + q0 + l15;
  if (QF32){
    const float* qp = (const float*)Qv + (size_t)qrow*q_rs + h*64 + g*8;
    #pragma unroll
    for (int kt=0;kt<2;kt++){
      bf16x8 v;
      #pragma unroll
      for (int j=0;j<8;j++) v[j] = (__bf16)qp[kt*32 + j];
      aq[kt]=v;
    }
  } else {
    const unsigned short* qp = (const unsigned short*)Qv + (size_t)qrow*q_rs + h*64 + g*8;
    aq[0] = *(const bf16x8*)(qp);
    aq[1] = *(const bf16x8*)(qp + 32);
  }
  const unsigned short* kbb = Kb + ((size_t)bh*256 + l15)*64 + g*8;
  f32x4 sc[16];
  #pragma unroll
  for (int nt=0;nt<16;nt++) sc[nt] = (f32x4){0.f,0.f,0.f,0.f};
  #pragma unroll
  for (int nt=0;nt<16;nt++){
    bf16x8 b0 = *(const bf16x8*)(kbb + (size_t)nt*1024);
    bf16x8 b1 = *(const bf16x8*)(kbb + (size_t)nt*1024 + 32);
    sc[nt] = __builtin_amdgcn_mfma_f32_16x16x32_bf16(aq[0], b0, sc[nt], 0,0,0);
    sc[nt] = __builtin_amdgcn_mfma_f32_16x16x32_bf16(aq[1], b1, sc[nt], 0,0,0);
  }
  float mx[4] = {-1e30f,-1e30f,-1e30f,-1e30f};
  #pragma unroll
  for (int nt=0;nt<16;nt++)
    #pragma unroll
    for (int r=0;r<4;r++){ float v = sc[nt][r]*scale; sc[nt][r]=v; mx[r]=fmaxf(mx[r],v); }
  #pragma unroll
  for (int r=0;r<4;r++){
    #pragma unroll
    for (int m=1;m<16;m<<=1) mx[r] = fmaxf(mx[r], __shfl_xor(mx[r], m));
  }
  float sum[4] = {0.f,0.f,0.f,0.f};
  #pragma unroll
  for (int nt=0;nt<16;nt++)
    #pragma unroll
    for (int r=0;r<4;r++){ float e = __expf(sc[nt][r]-mx[r]); sc[nt][r]=e; sum[r]+=e; }
  #pragma unroll
  for (int r=0;r<4;r++){
    #pragma unroll
    for (int m=1;m<16;m<<=1) sum[r] += __shfl_xor(sum[r], m);
  }
  f32x4 o[4];
  #pragma unroll
  for (int nd=0;nd<4;nd++) o[nd] = (f32x4){0.f,0.f,0.f,0.f};
  unsigned short* pw = Pw + w*640;
  const unsigned short* vb  = Vthi + ((size_t)bh*64 + l15)*256 + g*8;
  const unsigned short* vbl = SPLITV ? (Vtlo + ((size_t)bh*64 + l15)*256 + g*8) : (const unsigned short*)0;
  #pragma unroll
  for (int kt=0;kt<8;kt++){
    __builtin_amdgcn_wave_barrier();
    #pragma unroll
    for (int t2=0;t2<2;t2++){
      int nt = kt*2 + t2;
      #pragma unroll
      for (int r=0;r<4;r++)
        pw[(g*4+r)*40 + t2*16 + l15] = f2bf(sc[nt][r]);
    }
    __builtin_amdgcn_wave_barrier();
    bf16x8 ap = *(const bf16x8*)(pw + l15*40 + g*8);
    #pragma unroll
    for (int nd=0;nd<4;nd++){
      bf16x8 bv = *(const bf16x8*)(vb + (size_t)nd*4096 + kt*32);
      o[nd] = __builtin_amdgcn_mfma_f32_16x16x32_bf16(ap, bv, o[nd], 0,0,0);
      if (SPLITV){
        bf16x8 bl = *(const bf16x8*)(vbl + (size_t)nd*4096 + kt*32);
        o[nd] = __builtin_amdgcn_mfma_f32_16x16x32_bf16(ap, bl, o[nd], 0,0,0);
      }
    }
  }
  float inv[4];
  #pragma unroll
  for (int r=0;r<4;r++) inv[r] = 1.0f/sum[r];
  int orow0 = b*nper + q0;
  #pragma unroll
  for (int nd=0;nd<4;nd++){
    #pragma unroll
    for (int r=0;r<4;r++){
      float v = o[nd][r]*inv[r];
      size_t off = (size_t)(orow0 + g*4 + r)*o_rs + h*64 + nd*16 + l15;
      if (OSPLIT){ unsigned short hh,ll; split2(v,hh,ll); O0[off]=hh; O1[off]=ll; }
      else O0[off] = f2bf(v);
    }
  }
}

// ======================= fused LN29 + q-proj: data -> LN(ca) -> @WqT -> q_c bf16 ====
__global__ __launch_bounds__(256) void k_qproj_f(const float* __restrict__ X,
    const float* __restrict__ lng, const float* __restrict__ lnb,
    const unsigned short* __restrict__ Wt, unsigned short* __restrict__ Out)
{
  __shared__ __align__(16) unsigned short sm[128*40];
  int tid = threadIdx.x;
  int row0b = blockIdx.x*128;
  if (tid < 128){
    const float* x = X + (size_t)(row0b + tid)*29;
    float a[29]; float s = 0.f;
    #pragma unroll
    for (int k=0;k<29;k++){ a[k]=x[k]; s+=a[k]; }
    float mean = s*(1.0f/29.0f);
    float qv = 0.f;
    #pragma unroll
    for (int k=0;k<29;k++){ float d=a[k]-mean; qv+=d*d; }
    float rstd = rsqrtf(qv*(1.0f/29.0f) + 1e-5f);
    unsigned short yb[32] __attribute__((aligned(16)));
    #pragma unroll
    for (int k=0;k<29;k++) yb[k] = f2bf((a[k]-mean)*rstd*lng[k] + lnb[k]);
    yb[29]=0; yb[30]=0; yb[31]=0;
    uint4* d4 = (uint4*)(sm + tid*40);
    const uint4* s4 = (const uint4*)yb;
    d4[0]=s4[0]; d4[1]=s4[1]; d4[2]=s4[2]; d4[3]=s4[3];
  }
  __syncthreads();
  int lane = tid & 63, w = tid >> 6;
  int l15 = lane & 15, gq = lane >> 4;
  int rw = w*32;
  bf16x8 a0 = *(const bf16x8*)(sm + (rw + l15)*40 + gq*8);
  bf16x8 a1 = *(const bf16x8*)(sm + (rw + 16 + l15)*40 + gq*8);
  f32x4 acc[2][4];
  #pragma unroll
  for (int mt=0;mt<2;mt++)
    #pragma unroll
    for (int nt=0;nt<4;nt++) acc[mt][nt] = (f32x4){0.f,0.f,0.f,0.f};
  #pragma unroll
  for (int nt=0;nt<4;nt++){
    bf16x8 bw = *(const bf16x8*)(Wt + (size_t)(nt*16 + l15)*32 + gq*8);
    acc[0][nt] = __builtin_amdgcn_mfma_f32_16x16x32_bf16(a0, bw, acc[0][nt], 0,0,0);
    acc[1][nt] = __builtin_amdgcn_mfma_f32_16x16x32_bf16(a1, bw, acc[1][nt], 0,0,0);
  }
  #pragma unroll
  for (int mt=0;mt<2;mt++)
    #pragma unroll
    for (int nt=0;nt<4;nt++)
      #pragma unroll
      for (int r=0;r<4;r++)
        Out[(size_t)(row0b + rw + mt*16 + gq*4 + r)*64 + nt*16 + l15] = f2bf(acc[mt][nt][r]);
}

// ======================= data(Mx29) += A(MxK bf16) @ Wt(32xK)^T + bias =============
__global__ __launch_bounds__(256) void k_nsmall(const unsigned short* __restrict__ A,
    const unsigned short* __restrict__ Wt, const float* __restrict__ bias,
    float* __restrict__ C, int K)
{
  int tid = threadIdx.x, lane = tid & 63, w = tid >> 6;
  int l15 = lane & 15, g = lane >> 4;
  int row0 = blockIdx.x*128 + w*32;
  f32x4 acc[2][2];
  #pragma unroll
  for (int mt=0;mt<2;mt++)
    #pragma unroll
    for (int nt=0;nt<2;nt++) acc[mt][nt] = (f32x4){0.f,0.f,0.f,0.f};
  for (int kt=0; kt<K; kt+=32){
    bf16x8 a0 = *(const bf16x8*)(A + (size_t)(row0 + l15)*K + kt + g*8);
    bf16x8 a1 = *(const bf16x8*)(A + (size_t)(row0 + 16 + l15)*K + kt + g*8);
    #pragma unroll
    for (int nt=0;nt<2;nt++){
      bf16x8 bw = *(const bf16x8*)(Wt + (size_t)(nt*16 + l15)*K + kt + g*8);
      acc[0][nt] = __builtin_amdgcn_mfma_f32_16x16x32_bf16(a0, bw, acc[0][nt], 0,0,0);
      acc[1][nt] = __builtin_amdgcn_mfma_f32_16x16x32_bf16(a1, bw, acc[1][nt], 0,0,0);
    }
  }
  #pragma unroll
  for (int mt=0;mt<2;mt++)
    #pragma unroll
    for (int nt=0;nt<2;nt++){
      int col = nt*16 + l15;
      if (col < 29){
        #pragma unroll
        for (int r=0;r<4;r++){
          size_t off = (size_t)(row0 + mt*16 + g*4 + r)*29 + col;
          C[off] += acc[mt][nt][r] + bias[col];
        }
      }
    }
}

// ======================= fused LN29(cf) + FF1 + GEGLU -> gg_c bf16 (Mx128) =========
__global__ __launch_bounds__(256) void k_ff1_f(const float* __restrict__ X,
    const float* __restrict__ lng, const float* __restrict__ lnb,
    const unsigned short* __restrict__ Wt, const float* __restrict__ b1r,
    unsigned short* __restrict__ G)
{
  __shared__ __align__(16) unsigned short sm[128*40];
  int tid = threadIdx.x;
  int row0b = blockIdx.x*128;
  if (tid < 128){
    const float* x = X + (size_t)(row0b + tid)*29;
    float a[29]; float s = 0.f;
    #pragma unroll
    for (int k=0;k<29;k++){ a[k]=x[k]; s+=a[k]; }
    float mean = s*(1.0f/29.0f);
    float qv = 0.f;
    #pragma unroll
    for (int k=0;k<29;k++){ float d=a[k]-mean; qv+=d*d; }
    float rstd = rsqrtf(qv*(1.0f/29.0f) + 1e-5f);
    unsigned short yb[32] __attribute__((aligned(16)));
    #pragma unroll
    for (int k=0;k<29;k++) yb[k] = f2bf((a[k]-mean)*rstd*lng[k] + lnb[k]);
    yb[29]=0; yb[30]=0; yb[31]=0;
    uint4* d4 = (uint4*)(sm + tid*40);
    const uint4* s4 = (const uint4*)yb;
    d4[0]=s4[0]; d4[1]=s4[1]; d4[2]=s4[2]; d4[3]=s4[3];
  }
  __syncthreads();
  int lane = tid & 63, w = tid >> 6;
  int l15 = lane & 15, gq = lane >> 4;
  int rw = w*32;
  bf16x8 a0 = *(const bf16x8*)(sm + (rw + l15)*40 + gq*8);
  bf16x8 a1 = *(const bf16x8*)(sm + (rw + 16 + l15)*40 + gq*8);
  f32x4 acc[2][16];
  #pragma unroll
  for (int mt=0;mt<2;mt++)
    #pragma unroll
    for (int nt=0;nt<16;nt++) acc[mt][nt] = (f32x4){0.f,0.f,0.f,0.f};
  #pragma unroll
  for (int nt=0;nt<16;nt++){
    bf16x8 bw = *(const bf16x8*)(Wt + (size_t)(nt*16 + l15)*32 + gq*8);
    acc[0][nt] = __builtin_amdgcn_mfma_f32_16x16x32_bf16(a0, bw, acc[0][nt], 0,0,0);
    acc[1][nt] = __builtin_amdgcn_mfma_f32_16x16x32_bf16(a1, bw, acc[1][nt], 0,0,0);
  }
  #pragma unroll
  for (int mt=0;mt<2;mt++){
    #pragma unroll
    for (int t=0;t<8;t++){
      float ba = b1r[t*16 + l15];
      float bg = b1r[128 + t*16 + l15];
      #pragma unroll
      for (int r=0;r<4;r++){
        float av = acc[mt][t][r]   + ba;
        float gv = acc[mt][t+8][r] + bg;
        G[(size_t)(row0b + rw + mt*16 + gq*4 + r)*128 + t*16 + l15] = f2bf(av * gelu_exact(gv));
      }
    }
  }
}

// ======================= output =======================
__global__ __launch_bounds__(256) void k_out(const float* __restrict__ data, float* __restrict__ out)
{
  int idx = blockIdx.x*256 + threadIdx.x;
  int p = idx/3, c = idx - p*3;
  out[idx] = data[(size_t)p*29 + c];
}

// =====================================================================
extern "C" void kernel_launch(void* const* d_in, const int* in_sizes, int n_in,
                              void* d_out, int out_size, void* d_ws, size_t ws_size,
                              hipStream_t stream) {
  const float* x        = (const float*)d_in[0];
  const float* latents  = (const float*)d_in[1];
  const float* W_l2l    = (const float*)d_in[2];
  const float* b_l2l    = (const float*)d_in[3];
  const float* ca_ln_q_g= (const float*)d_in[4];
  const float* ca_ln_q_b= (const float*)d_in[5];
  const float* ca_ln_c_g= (const float*)d_in[6];
  const float* ca_ln_c_b= (const float*)d_in[7];
  const float* ca_Wq    = (const float*)d_in[8];
  const float* ca_Wkv   = (const float*)d_in[9];
  const float* ca_Wo    = (const float*)d_in[10];
  const float* ca_bo    = (const float*)d_in[11];
  const float* cf_ln_g  = (const float*)d_in[12];
  const float* cf_ln_b  = (const float*)d_in[13];
  const float* cf_W1    = (const float*)d_in[14];
  const float* cf_b1    = (const float*)d_in[15];
  const float* cf_W2    = (const float*)d_in[16];
  const float* cf_b2    = (const float*)d_in[17];
  const float* la_ln_g  = (const float*)d_in[18];
  const float* la_ln_b  = (const float*)d_in[19];
  const float* la_Wq    = (const float*)d_in[20];
  const float* la_Wkv   = (const float*)d_in[21];
  const float* la_Wo    = (const float*)d_in[22];
  const float* la_bo    = (const float*)d_in[23];
  const float* lf_ln_g  = (const float*)d_in[24];
  const float* lf_ln_b  = (const float*)d_in[25];
  const float* lf_W1    = (const float*)d_in[26];
  const float* lf_b1    = (const float*)d_in[27];
  const float* lf_W2    = (const float*)d_in[28];
  const float* lf_b2    = (const float*)d_in[29];

  float* ws = (float*)d_ws;
  // ---- layout (floats) ----
  float* data = ws;                                   // 3,801,088
  float* lat  = ws + 3801088;                         // 1,048,576
  unsigned short* latn_hi = (unsigned short*)(ws + 4849664); // 2048*512 hi|lo
  unsigned short* latn_lo = latn_hi + 1048576;
  float* I    = ws + 5898240;                         // 14,680,064 arena
  float* kv_c = ws + 20578304;                        // 4 x 262,144 z-partials
  unsigned short* Kb_c = (unsigned short*)(ws + 21626880);   // 131,072 ush
  unsigned short* Vt_c = Kb_c + 131072;                      // 131,072 ush
  unsigned short* wsp  = (unsigned short*)(ws + 21757952);   // 4 x LSTRIDE ush
  // arena I aliases (temporally disjoint):
  float* q_l  = I;                                      // 2048x512 f
  float* kv_l = I + 1048576;                            // 2048x1024 f
  unsigned short* Kb_l   = (unsigned short*)(I + 3145728);  // 64*256*64
  unsigned short* Vthi_l = Kb_l + 1048576;
  unsigned short* Vtlo_l = Vthi_l + 1048576;
  unsigned short* ao_hi  = (unsigned short*)(I + 4718592);  // 2048x512 hi|lo
  unsigned short* ao_lo  = ao_hi + 1048576;
  unsigned short* gg_hi = (unsigned short*)(I + 8388608);   // 2048x2048 hi|lo
  unsigned short* gg_lo = gg_hi + 4194304;
  unsigned short* q_c  = (unsigned short*)(I + 2097152);    // 131072x64
  unsigned short* gg_c = (unsigned short*)(I + 6291456);    // 131072x128

  k_encode<<<64, 256, 0, stream>>>(data);
  k_l2l   <<<512, 256, 0, stream>>>(x, W_l2l, b_l2l, latents, lat);

  // ---- all-layer weight preps (batched over z) ----
  k_split_w<<<dim3(8,8,4),  256,0,stream>>>(la_Wq,  wsp,          512, 512);
  k_split_w<<<dim3(8,16,4), 256,0,stream>>>(la_Wkv, wsp+524288,   512, 1024);
  k_split_w<<<dim3(8,8,4),  256,0,stream>>>(la_Wo,  wsp+1572864,  512, 512);
  k_split_w<<<dim3(8,64,4), 256,0,stream>>>(lf_W1,  wsp+2097152,  512, 4096);
  k_split_w<<<dim3(32,8,4), 256,0,stream>>>(lf_W2,  wsp+6291456,  2048, 512);
  k_split_w<<<dim3(8,2,4),  256,0,stream>>>(ca_Wkv, wsp+8388608,  512, 128);
  k_prep_t <<<dim3(4,1,4),256,0,stream>>>(ca_Wq, wsp+8519680, 29, 64, 32, 64);
  k_prep_t <<<dim3(4,1,4),256,0,stream>>>(ca_Wo, wsp+8521728, 64, 29, 64, 32);
  k_prep_t <<<dim3(8,1,4),256,0,stream>>>(cf_W2, wsp+8523776, 116, 29, 128, 32);
  k_prep_w1<<<dim3(32,1,4),256,0,stream>>>(cf_W1, cf_b1, wsp+8527872);

  for (int i=0;i<4;i++){
    unsigned short* wl = wsp + (size_t)i*LSTRIDE;
    unsigned short* wqt  = wl;
    unsigned short* wkvt = wl + 524288;
    unsigned short* wot  = wl + 1572864;
    unsigned short* w1t  = wl + 2097152;
    unsigned short* w2t  = wl + 6291456;
    unsigned short* cakvt= wl + 8388608;
    unsigned short* WqT  = wl + 8519680;
    unsigned short* WoT  = wl + 8521728;
    unsigned short* W2T  = wl + 8523776;
    unsigned short* W1rT = wl + 8527872;
    float* b1r = (float*)(wl + 8536064);

    // ---- latent self-attention ----
    k_ln512s<<<2048,256,0,stream>>>(lat, la_ln_g+i*512, la_ln_b+i*512, latn_hi, latn_lo);
    k_mfma<<<dim3(16,4,1),256,0,stream>>>(latn_hi, wqt,  nullptr, q_l,  2048, 512, 512, 1, 0);
    k_mfma<<<dim3(16,8,1),256,0,stream>>>(latn_hi, wkvt, nullptr, kv_l, 2048,1024, 512, 1, 0);
    k_kvprep<<<1024,256,0,stream>>>(kv_l, 1024, 0, 512, 8, 64, Kb_l, Vthi_l, Vtlo_l, 1, 0);
    k_attn_mf<1,1,1><<<256,256,0,stream>>>(q_l, Kb_l, Vthi_l, Vtlo_l, ao_hi, ao_lo,
                                           512, 512, 8, 256, 0.125f);
    k_mfma<<<dim3(16,4,2),256,0,stream>>>(ao_hi, wot, la_bo+i*512, lat, 2048, 512, 512, 2, 1);
    // ---- latent GEGLU FF (fused FF1+GEGLU) ----
    k_ln512s<<<2048,256,0,stream>>>(lat, lf_ln_g+i*512, lf_ln_b+i*512, latn_hi, latn_lo);
    k_mfma_glu<<<dim3(16,32),256,0,stream>>>(latn_hi, w1t, lf_b1+i*4096, gg_hi, gg_lo);
    k_mfma<<<dim3(16,4,4),256,0,stream>>>(gg_hi, w2t, lf_b2+i*512, lat, 2048, 512, 2048, 4, 1);
    // ---- cross-attention ----
    k_ln512s<<<2048,256,0,stream>>>(lat, ca_ln_c_g+i*512, ca_ln_c_b+i*512, latn_hi, latn_lo);
    k_mfma<<<dim3(16,1,4),256,0,stream>>>(latn_hi, cakvt, nullptr, kv_c, 2048, 128, 512, 4, 0);
    k_kvprep<<<512,256,0,stream>>>(kv_c, 128, 0, 64, 1, 8, Kb_c, Vt_c, nullptr, 4, 262144);
    k_qproj_f<<<1024,256,0,stream>>>(data, ca_ln_q_g+i*29, ca_ln_q_b+i*29, WqT, q_c);
    k_attn_mf<0,0,0><<<2048,256,0,stream>>>(q_c, Kb_c, Vt_c, nullptr, q_c, nullptr,
                                            64, 64, 1, 16384, 0.125f);
    k_nsmall<<<1024,256,0,stream>>>(q_c, WoT, ca_bo+i*29, data, 64);
    // ---- cross GEGLU FF (fused LN+FF1+GEGLU) ----
    k_ff1_f<<<1024,256,0,stream>>>(data, cf_ln_g+i*29, cf_ln_b+i*29, W1rT, b1r, gg_c);
    k_nsmall<<<1024,256,0,stream>>>(gg_c, W2T, cf_b2+i*29, data, 128);
  }

  k_out<<<1536,256,0,stream>>>(data, (float*)d_out);
}

// Round 2
// 1862.728 us; speedup vs baseline: 1.0727x; 1.0409x over previous
//
#include <hip/hip_runtime.h>
#include <math.h>

#define DEV __device__ __forceinline__
#define LSTRIDE 8537088

DEV float gelu_exact(float x){ return 0.5f*x*(1.0f+erff(x*0.70710678118654752440f)); }

DEV unsigned short f2bf(float x){
  union { float f; unsigned int u; } v; v.f = x;
  unsigned int r = v.u + 0x7FFFu + ((v.u >> 16) & 1u);
  return (unsigned short)(r >> 16);
}
DEV float bf2f(unsigned short b){ union { unsigned int u; float f; } v; v.u = ((unsigned int)b)<<16; return v.f; }
DEV void split2(float x, unsigned short& h, unsigned short& l){
  h = f2bf(x); l = f2bf(x - bf2f(h));
}

typedef __bf16 bf16x8 __attribute__((ext_vector_type(8)));
typedef float  f32x4  __attribute__((ext_vector_type(4)));

DEV void gload16(const void* g, void* lds){
  __builtin_amdgcn_global_load_lds((const __attribute__((address_space(1))) unsigned int*)g,
                                   (__attribute__((address_space(3))) unsigned int*)lds, 16, 0, 0);
}

// ======================= Fourier-encode data grid =======================
__global__ __launch_bounds__(256) void k_encode(float* __restrict__ data)
{
  int p = blockIdx.x*256 + threadIdx.x;
  int hh = p >> 7, ww = p & 127;
  float y = -1.0f + hh*(2.0f/127.0f);
  float x = -1.0f + ww*(2.0f/127.0f);
  float e[26];
  #pragma unroll
  for (int i=0;i<6;i++){
    float sc = exp2f(1.0f + i*0.26438561897747245f) * 3.14159265358979323846f;
    e[i]     = sinf(y*sc);
    e[6+i]   = cosf(y*sc);
    e[13+i]  = sinf(x*sc);
    e[19+i]  = cosf(x*sc);
  }
  e[12]=y; e[25]=x;
  #pragma unroll
  for (int b=0;b<8;b++){
    float* dr = data + ((size_t)(b*16384 + p))*29;
    dr[0]=0.f; dr[1]=0.f; dr[2]=0.f;
    #pragma unroll
    for (int c=0;c<26;c++) dr[3+c]=e[c];
  }
}

// ======================= lat = x @ W_l2l + b + latents =======================
__global__ __launch_bounds__(256) void k_l2l(const float* __restrict__ x,
    const float* __restrict__ Wl, const float* __restrict__ bl,
    const float* __restrict__ latents, float* __restrict__ lat)
{
  __shared__ float xs[8*512];
  int tid = threadIdx.x;
  for (int idx=tid; idx<4096; idx+=256) xs[idx]=x[idx];
  __syncthreads();
  int nIdx = blockIdx.x*256 + tid;
  float acc[8] = {0,0,0,0,0,0,0,0};
  for (int k=0;k<512;k++){
    float w = Wl[(size_t)k*131072 + nIdx];
    #pragma unroll
    for (int m=0;m<8;m++) acc[m] += xs[m*512+k]*w;
  }
  float add = bl[nIdx] + latents[nIdx];
  #pragma unroll
  for (int m=0;m<8;m++) lat[(size_t)m*131072 + nIdx] = acc[m] + add;
}

// ======================= LayerNorm D=512 -> split bf16 hi/lo =======================
__global__ __launch_bounds__(256) void k_ln512s(const float* __restrict__ X,
    const float* __restrict__ g, const float* __restrict__ bv,
    unsigned short* __restrict__ hi, unsigned short* __restrict__ lo)
{
  __shared__ float red[8];
  int row = blockIdx.x, tid = threadIdx.x;
  const float* x = X + (size_t)row*512;
  float v0 = x[tid], v1 = x[tid+256];
  float s = v0+v1;
  #pragma unroll
  for (int off=32; off; off>>=1) s += __shfl_xor(s, off);
  if ((tid&63)==0) red[tid>>6] = s;
  __syncthreads();
  float mean = (red[0]+red[1]+red[2]+red[3]) * (1.0f/512.0f);
  float d0 = v0-mean, d1 = v1-mean;
  float q = d0*d0 + d1*d1;
  #pragma unroll
  for (int off=32; off; off>>=1) q += __shfl_xor(q, off);
  if ((tid&63)==0) red[4+(tid>>6)] = q;
  __syncthreads();
  float var = (red[4]+red[5]+red[6]+red[7]) * (1.0f/512.0f);
  float rstd = rsqrtf(var + 1e-5f);
  float y0 = d0*rstd*g[tid]     + bv[tid];
  float y1 = d1*rstd*g[tid+256] + bv[tid+256];
  unsigned short h,l;
  split2(y0,h,l); hi[(size_t)row*512+tid]=h;     lo[(size_t)row*512+tid]=l;
  split2(y1,h,l); hi[(size_t)row*512+tid+256]=h; lo[(size_t)row*512+tid+256]=l;
}

// ======================= weight split+transpose, batched over layers (z) ==========
// W(KxN) layer stride K*N -> combined Wt: hi rows at n0off+n, lo = hi + Ntot*K
__global__ __launch_bounds__(256) void k_split_w(const float* __restrict__ W,
    unsigned short* __restrict__ hi, int K, int N, int Ntot, int n0off)
{
  __shared__ float t[64][65];
  int z = blockIdx.z;
  W  += (size_t)z*K*N;
  hi += (size_t)z*LSTRIDE;
  unsigned short* lo = hi + (size_t)Ntot*K;
  int k0 = blockIdx.x*64, n0 = blockIdx.y*64;
  int tid = threadIdx.x;
  #pragma unroll
  for (int i=0;i<4;i++){
    int s = tid + 256*i;
    int r = s >> 4, c4 = (s & 15)*4;
    float4 v = *(const float4*)&W[(size_t)(k0+r)*N + n0 + c4];
    t[r][c4+0]=v.x; t[r][c4+1]=v.y; t[r][c4+2]=v.z; t[r][c4+3]=v.w;
  }
  __syncthreads();
  #pragma unroll
  for (int i=0;i<4;i++){
    int s = tid + 256*i;
    int n = s >> 4, kc = (s & 15)*4;
    size_t o = (size_t)(n0off + n0 + n)*K + k0 + kc;
    #pragma unroll
    for (int j=0;j<4;j++){
      unsigned short h,l; split2(t[kc+j][n], h, l);
      hi[o+j]=h; lo[o+j]=l;
    }
  }
}

// ======================= generic small transpose, batched over layers (z) =========
__global__ __launch_bounds__(256) void k_prep_t(const float* __restrict__ src,
    unsigned short* __restrict__ dst, int K, int N, int Kd, int Nd)
{
  int z = blockIdx.z;
  src += (size_t)z*K*N;
  dst += (size_t)z*LSTRIDE;
  for (int idx = blockIdx.x*256 + threadIdx.x; idx < Nd*Kd; idx += gridDim.x*256){
    int n = idx / Kd, k = idx - n*Kd;
    float v = (k<K && n<N) ? src[(size_t)k*N + n] : 0.f;
    dst[idx] = f2bf(v);
  }
}

// ======================= W1 reorder+transpose (batched): (29x232)->(256x32), b1->b1r
__global__ __launch_bounds__(256) void k_prep_w1(const float* __restrict__ W1,
    const float* __restrict__ b1, unsigned short* __restrict__ dst)
{
  int z = blockIdx.z;
  W1  += (size_t)z*6728;
  b1  += (size_t)z*232;
  dst += (size_t)z*LSTRIDE;
  float* b1r = (float*)(dst + 8192);
  for (int idx = blockIdx.x*256 + threadIdx.x; idx < 256*32; idx += gridDim.x*256){
    int n = idx >> 5, k = idx & 31;
    int f = n & 127, isg = n >> 7;
    float v = 0.f;
    if (f < 116 && k < 29) v = W1[(size_t)k*232 + isg*116 + f];
    dst[idx] = f2bf(v);
  }
  int n = blockIdx.x*256 + threadIdx.x;
  if (n < 256){
    int f = n & 127, isg = n >> 7;
    b1r[n] = (f < 116) ? b1[isg*116 + f] : 0.f;
  }
}

// ======================= split-bf16 MFMA GEMM (latent path) =============
__global__ __launch_bounds__(256) void k_mfma(
    const unsigned short* __restrict__ Ahi, const unsigned short* __restrict__ Bhi,
    const float* __restrict__ bias, float* __restrict__ C,
    int M, int N, int K, int Ksplit, int accum)
{
  __shared__ unsigned short sm[4*128*32];
  int tid = threadIdx.x, lane = tid & 63, w = tid >> 6;
  int bm = blockIdx.x*128, bn = blockIdx.y*128;
  int Ks = K / Ksplit;
  int kbeg = blockIdx.z * Ks;
  const unsigned short* tsrc;
  if      (w==0) tsrc = Ahi + (size_t)bm*K;
  else if (w==1) tsrc = Ahi + (size_t)M*K + (size_t)bm*K;
  else if (w==2) tsrc = Bhi + (size_t)bn*K;
  else           tsrc = Bhi + (size_t)N*K + (size_t)bn*K;
  unsigned short* mylds = sm + w*4096;
  f32x4 acc[4][4];
  #pragma unroll
  for(int i=0;i<4;i++)
    #pragma unroll
    for(int j=0;j<4;j++) acc[i][j] = (f32x4){0.f,0.f,0.f,0.f};
  int wm = (w>>1)*64, wn = (w&1)*64;
  int frow = lane & 15, fq = lane >> 4;
  for (int k0 = kbeg; k0 < kbeg + Ks; k0 += 32){
    #pragma unroll
    for (int j=0;j<8;j++){
      int idx = j*64 + lane;
      int row = idx >> 2, qp = idx & 3;
      int q = (qp - row) & 3;
      gload16(tsrc + (size_t)row*K + k0 + q*8, mylds + j*512);
    }
    __syncthreads();
    bf16x8 ah[4], al[4];
    #pragma unroll
    for (int mt=0;mt<4;mt++){
      int row = wm + mt*16 + frow;
      int off = row*32 + ((fq + row)&3)*8;
      ah[mt] = *(const bf16x8*)(sm + off);
      al[mt] = *(const bf16x8*)(sm + 4096 + off);
    }
    #pragma unroll
    for (int nt=0;nt<4;nt++){
      int rowb = wn + nt*16 + frow;
      int offb = rowb*32 + ((fq + rowb)&3)*8;
      bf16x8 bh = *(const bf16x8*)(sm + 2*4096 + offb);
      bf16x8 bl = *(const bf16x8*)(sm + 3*4096 + offb);
      #pragma unroll
      for (int mt=0;mt<4;mt++){
        acc[mt][nt] = __builtin_amdgcn_mfma_f32_16x16x32_bf16(ah[mt], bh, acc[mt][nt], 0,0,0);
        acc[mt][nt] = __builtin_amdgcn_mfma_f32_16x16x32_bf16(ah[mt], bl, acc[mt][nt], 0,0,0);
        acc[mt][nt] = __builtin_amdgcn_mfma_f32_16x16x32_bf16(al[mt], bh, acc[mt][nt], 0,0,0);
      }
    }
    __syncthreads();
  }
  size_t zoff = (size_t)blockIdx.z * ((size_t)M*N);
  #pragma unroll
  for (int mt=0;mt<4;mt++){
    #pragma unroll
    for (int nt=0;nt<4;nt++){
      int col = bn + wn + nt*16 + frow;
      float bv = (bias && blockIdx.z==0) ? bias[col] : 0.f;
      #pragma unroll
      for (int r=0;r<4;r++){
        int row = bm + wm + mt*16 + fq*4 + r;
        float v = acc[mt][nt][r] + bv;
        if (accum) atomicAdd(&C[(size_t)row*N + col], v);
        else       C[zoff + (size_t)row*N + col] = v;
      }
    }
  }
}

// ======================= fused latent QKV GEMM: N=1536, epilogue writes q fp32,
// K bf16 (bh*256+j,64), V split-transposed (bh*64+d,256)
__global__ __launch_bounds__(256) void k_mfma_qkv(
    const unsigned short* __restrict__ Ahi, const unsigned short* __restrict__ Bhi,
    float* __restrict__ qout, unsigned short* __restrict__ Kb,
    unsigned short* __restrict__ Vthi, unsigned short* __restrict__ Vtlo,
    int M, int N, int K)
{
  __shared__ unsigned short sm[4*128*32];
  int tid = threadIdx.x, lane = tid & 63, w = tid >> 6;
  int bm = blockIdx.x*128, bn = blockIdx.y*128;
  const unsigned short* tsrc;
  if      (w==0) tsrc = Ahi + (size_t)bm*K;
  else if (w==1) tsrc = Ahi + (size_t)M*K + (size_t)bm*K;
  else if (w==2) tsrc = Bhi + (size_t)bn*K;
  else           tsrc = Bhi + (size_t)N*K + (size_t)bn*K;
  unsigned short* mylds = sm + w*4096;
  f32x4 acc[4][4];
  #pragma unroll
  for(int i=0;i<4;i++)
    #pragma unroll
    for(int j=0;j<4;j++) acc[i][j] = (f32x4){0.f,0.f,0.f,0.f};
  int wm = (w>>1)*64, wn = (w&1)*64;
  int frow = lane & 15, fq = lane >> 4;
  for (int k0 = 0; k0 < K; k0 += 32){
    #pragma unroll
    for (int j=0;j<8;j++){
      int idx = j*64 + lane;
      int row = idx >> 2, qp = idx & 3;
      int q = (qp - row) & 3;
      gload16(tsrc + (size_t)row*K + k0 + q*8, mylds + j*512);
    }
    __syncthreads();
    bf16x8 ah[4], al[4];
    #pragma unroll
    for (int mt=0;mt<4;mt++){
      int row = wm + mt*16 + frow;
      int off = row*32 + ((fq + row)&3)*8;
      ah[mt] = *(const bf16x8*)(sm + off);
      al[mt] = *(const bf16x8*)(sm + 4096 + off);
    }
    #pragma unroll
    for (int nt=0;nt<4;nt++){
      int rowb = wn + nt*16 + frow;
      int offb = rowb*32 + ((fq + rowb)&3)*8;
      bf16x8 bh = *(const bf16x8*)(sm + 2*4096 + offb);
      bf16x8 bl = *(const bf16x8*)(sm + 3*4096 + offb);
      #pragma unroll
      for (int mt=0;mt<4;mt++){
        acc[mt][nt] = __builtin_amdgcn_mfma_f32_16x16x32_bf16(ah[mt], bh, acc[mt][nt], 0,0,0);
        acc[mt][nt] = __builtin_amdgcn_mfma_f32_16x16x32_bf16(ah[mt], bl, acc[mt][nt], 0,0,0);
        acc[mt][nt] = __builtin_amdgcn_mfma_f32_16x16x32_bf16(al[mt], bh, acc[mt][nt], 0,0,0);
      }
    }
    __syncthreads();
  }
  #pragma unroll
  for (int mt=0;mt<4;mt++){
    #pragma unroll
    for (int nt=0;nt<4;nt++){
      int col = bn + wn + nt*16 + frow;
      #pragma unroll
      for (int r=0;r<4;r++){
        int row = bm + wm + mt*16 + fq*4 + r;
        float v = acc[mt][nt][r];
        int b = row >> 8, j = row & 255;
        if (col < 512){
          qout[(size_t)row*512 + col] = v;
        } else if (col < 1024){
          int kc = col - 512, h = kc >> 6, d = kc & 63;
          Kb[((size_t)((b*8+h)*256 + j))*64 + d] = f2bf(v);
        } else {
          int vc = col - 1024, h = vc >> 6, d = vc & 63;
          size_t idx = ((size_t)((b*8+h)*64 + d))*256 + j;
          unsigned short hh,ll; split2(v,hh,ll);
          Vthi[idx]=hh; Vtlo[idx]=ll;
        }
      }
    }
  }
}

// ======================= fused latent FF1 + GEGLU (split-bf16 in, split-bf16 out) ===
__global__ __launch_bounds__(256) void k_mfma_glu(
    const unsigned short* __restrict__ Ahi, const unsigned short* __restrict__ Whi,
    const float* __restrict__ b1, unsigned short* __restrict__ Ghi,
    unsigned short* __restrict__ Glo)
{
  __shared__ unsigned short sm[16384];
  int tid = threadIdx.x, lane = tid & 63, w = tid >> 6;
  int bm = blockIdx.x*128, bnp = blockIdx.y*64;
  const unsigned short* Alo = Ahi + (size_t)2048*512;
  const unsigned short* Wlo = Whi + (size_t)4096*512;
  f32x4 aa[4][2], ag[4][2];
  #pragma unroll
  for (int i=0;i<4;i++)
    #pragma unroll
    for (int j=0;j<2;j++){ aa[i][j]=(f32x4){0.f,0.f,0.f,0.f}; ag[i][j]=(f32x4){0.f,0.f,0.f,0.f}; }
  int wm = (w>>1)*64, wnp = (w&1)*32;
  int frow = lane & 15, fq = lane >> 4;
  for (int k0=0;k0<512;k0+=32){
    #pragma unroll
    for (int j=0;j<8;j++){
      int c0 = w*512 + j*64;
      int c  = c0 + lane;
      int sel = c0 >> 8;
      const unsigned short* src; int wi;
      if (sel < 4){
        src = (sel < 2 ? Ahi : Alo) + (size_t)bm*512;
        wi = c & 511;
      } else {
        const unsigned short* wb = (sel < 6) ? Whi : Wlo;
        int cb = bnp + ((sel & 1) ? 2048 : 0);
        src = wb + (size_t)cb*512;
        wi = c & 255;
      }
      int row = wi >> 2, qp = wi & 3;
      int q = (qp - row) & 3;
      gload16(src + (size_t)row*512 + k0 + q*8, sm + c0*8);
    }
    __syncthreads();
    bf16x8 ah[4], al[4];
    #pragma unroll
    for (int mt=0;mt<4;mt++){
      int r = wm + mt*16 + frow;
      int off = r*32 + ((fq + r)&3)*8;
      ah[mt] = *(const bf16x8*)(sm + off);
      al[mt] = *(const bf16x8*)(sm + 4096 + off);
    }
    #pragma unroll
    for (int nt=0;nt<2;nt++){
      int rb = wnp + nt*16 + frow;
      int offb = rb*32 + ((fq + rb)&3)*8;
      bf16x8 bah = *(const bf16x8*)(sm +  8192 + offb);
      bf16x8 bgh = *(const bf16x8*)(sm + 10240 + offb);
      bf16x8 bal = *(const bf16x8*)(sm + 12288 + offb);
      bf16x8 bgl = *(const bf16x8*)(sm + 14336 + offb);
      #pragma unroll
      for (int mt=0;mt<4;mt++){
        aa[mt][nt] = __builtin_amdgcn_mfma_f32_16x16x32_bf16(ah[mt], bah, aa[mt][nt], 0,0,0);
        aa[mt][nt] = __builtin_amdgcn_mfma_f32_16x16x32_bf16(ah[mt], bal, aa[mt][nt], 0,0,0);
        aa[mt][nt] = __builtin_amdgcn_mfma_f32_16x16x32_bf16(al[mt], bah, aa[mt][nt], 0,0,0);
        ag[mt][nt] = __builtin_amdgcn_mfma_f32_16x16x32_bf16(ah[mt], bgh, ag[mt][nt], 0,0,0);
        ag[mt][nt] = __builtin_amdgcn_mfma_f32_16x16x32_bf16(ah[mt], bgl, ag[mt][nt], 0,0,0);
        ag[mt][nt] = __builtin_amdgcn_mfma_f32_16x16x32_bf16(al[mt], bgh, ag[mt][nt], 0,0,0);
      }
    }
    __syncthreads();
  }
  #pragma unroll
  for (int mt=0;mt<4;mt++){
    #pragma unroll
    for (int nt=0;nt<2;nt++){
      int col = bnp + wnp + nt*16 + frow;
      float ba = b1[col], bg = b1[2048+col];
      #pragma unroll
      for (int r=0;r<4;r++){
        int row = bm + wm + mt*16 + fq*4 + r;
        float av = aa[mt][nt][r] + ba;
        float gv = ag[mt][nt][r] + bg;
        unsigned short h,l; split2(av*gelu_exact(gv), h, l);
        Ghi[(size_t)row*2048 + col] = h;
        Glo[(size_t)row*2048 + col] = l;
      }
    }
  }
}

// ======================= KV prep (cross): kv fp32 z-partials summed -> Kb/Vt bf16 ===
__global__ __launch_bounds__(256) void k_kvprep(const float* __restrict__ kv, int ld,
    int koff, int voff, int heads, int BH,
    unsigned short* __restrict__ Kb, unsigned short* __restrict__ Vthi,
    unsigned short* __restrict__ Vtlo, int zparts, int zstride)
{
  int total = BH << 14;
  for (int idx = blockIdx.x*256 + threadIdx.x; idx < total; idx += gridDim.x*256){
    int d = idx & 63, j = (idx>>6) & 255, bh = idx >> 14;
    int b = bh / heads, h = bh - b*heads;
    size_t base = ((size_t)(b*256 + j))*ld + koff + h*64 + d;
    float v = 0.f;
    for (int z=0; z<zparts; z++) v += kv[(size_t)z*zstride + base];
    Kb[idx] = f2bf(v);
  }
  for (int idx = blockIdx.x*256 + threadIdx.x; idx < total; idx += gridDim.x*256){
    int j = idx & 255, d = (idx>>8) & 63, bh = idx >> 14;
    int b = bh / heads, h = bh - b*heads;
    size_t base = ((size_t)(b*256 + j))*ld + voff + h*64 + d;
    float v = 0.f;
    for (int z=0; z<zparts; z++) v += kv[(size_t)z*zstride + base];
    if (Vtlo){ unsigned short hh,ll; split2(v,hh,ll); Vthi[idx]=hh; Vtlo[idx]=ll; }
    else Vthi[idx] = f2bf(v);
  }
}

// ======================= MFMA attention (latent): 16 queries/wave, 256 keys, dh=64 ==
template<int QF32, int SPLITV, int OSPLIT>
__global__ __launch_bounds__(256) void k_attn_mf(
    const void* __restrict__ Qv, const unsigned short* __restrict__ Kb,
    const unsigned short* __restrict__ Vthi, const unsigned short* __restrict__ Vtlo,
    unsigned short* __restrict__ O0, unsigned short* __restrict__ O1,
    int q_rs, int o_rs, int heads, int nper, float scale)
{
  __shared__ unsigned short Pw[4*640];
  int tid = threadIdx.x, lane = tid & 63, w = tid >> 6;
  int l15 = lane & 15, g = lane >> 4;
  int bpb = nper >> 6;
  int bh = blockIdx.x / bpb;
  int q0 = (blockIdx.x - bh*bpb)*64 + w*16;
  int b = bh / heads, h = bh - b*heads;
  bf16x8 aq[2];
  int qrow = b*nper + q0 + l15;
  if (QF32){
    const float* qp = (const float*)Qv + (size_t)qrow*q_rs + h*64 + g*8;
    #pragma unroll
    for (int kt=0;kt<2;kt++){
      bf16x8 v;
      #pragma unroll
      for (int j=0;j<8;j++) v[j] = (__bf16)qp[kt*32 + j];
      aq[kt]=v;
    }
  } else {
    const unsigned short* qp = (const unsigned short*)Qv + (size_t)qrow*q_rs + h*64 + g*8;
    aq[0] = *(const bf16x8*)(qp);
    aq[1] = *(const bf16x8*)(qp + 32);
  }
  const unsigned short* kbb = Kb + ((size_t)bh*256 + l15)*64 + g*8;
  f32x4 sc[16];
  #pragma unroll
  for (int nt=0;nt<16;nt++) sc[nt] = (f32x4){0.f,0.f,0.f,0.f};
  #pragma unroll
  for (int nt=0;nt<16;nt++){
    bf16x8 b0 = *(const bf16x8*)(kbb + (size_t)nt*1024);
    bf16x8 b1 = *(const bf16x8*)(kbb + (size_t)nt*1024 + 32);
    sc[nt] = __builtin_amdgcn_mfma_f32_16x16x32_bf16(aq[0], b0, sc[nt], 0,0,0);
    sc[nt] = __builtin_amdgcn_mfma_f32_16x16x32_bf16(aq[1], b1, sc[nt], 0,0,0);
  }
  float mx[4] = {-1e30f,-1e30f,-1e30f,-1e30f};
  #pragma unroll
  for (int nt=0;nt<16;nt++)
    #pragma unroll
    for (int r=0;r<4;r++){ float v = sc[nt][r]*scale; sc[nt][r]=v; mx[r]=fmaxf(mx[r],v); }
  #pragma unroll
  for (int r=0;r<4;r++){
    #pragma unroll
    for (int m=1;m<16;m<<=1) mx[r] = fmaxf(mx[r], __shfl_xor(mx[r], m));
  }
  float sum[4] = {0.f,0.f,0.f,0.f};
  #pragma unroll
  for (int nt=0;nt<16;nt++)
    #pragma unroll
    for (int r=0;r<4;r++){ float e = __expf(sc[nt][r]-mx[r]); sc[nt][r]=e; sum[r]+=e; }
  #pragma unroll
  for (int r=0;r<4;r++){
    #pragma unroll
    for (int m=1;m<16;m<<=1) sum[r] += __shfl_xor(sum[r], m);
  }
  f32x4 o[4];
  #pragma unroll
  for (int nd=0;nd<4;nd++) o[nd] = (f32x4){0.f,0.f,0.f,0.f};
  unsigned short* pw = Pw + w*640;
  const unsigned short* vb  = Vthi + ((size_t)bh*64 + l15)*256 + g*8;
  const unsigned short* vbl = SPLITV ? (Vtlo + ((size_t)bh*64 + l15)*256 + g*8) : (const unsigned short*)0;
  #pragma unroll
  for (int kt=0;kt<8;kt++){
    __builtin_amdgcn_wave_barrier();
    #pragma unroll
    for (int t2=0;t2<2;t2++){
      int nt = kt*2 + t2;
      #pragma unroll
      for (int r=0;r<4;r++)
        pw[(g*4+r)*40 + t2*16 + l15] = f2bf(sc[nt][r]);
    }
    __builtin_amdgcn_wave_barrier();
    bf16x8 ap = *(const bf16x8*)(pw + l15*40 + g*8);
    #pragma unroll
    for (int nd=0;nd<4;nd++){
      bf16x8 bv = *(const bf16x8*)(vb + (size_t)nd*4096 + kt*32);
      o[nd] = __builtin_amdgcn_mfma_f32_16x16x32_bf16(ap, bv, o[nd], 0,0,0);
      if (SPLITV){
        bf16x8 bl = *(const bf16x8*)(vbl + (size_t)nd*4096 + kt*32);
        o[nd] = __builtin_amdgcn_mfma_f32_16x16x32_bf16(ap, bl, o[nd], 0,0,0);
      }
    }
  }
  float inv[4];
  #pragma unroll
  for (int r=0;r<4;r++) inv[r] = 1.0f/sum[r];
  int orow0 = b*nper + q0;
  #pragma unroll
  for (int nd=0;nd<4;nd++){
    #pragma unroll
    for (int r=0;r<4;r++){
      float v = o[nd][r]*inv[r];
      size_t off = (size_t)(orow0 + g*4 + r)*o_rs + h*64 + nd*16 + l15;
      if (OSPLIT){ unsigned short hh,ll; split2(v,hh,ll); O0[off]=hh; O1[off]=ll; }
      else O0[off] = f2bf(v);
    }
  }
}

// ======================= fully fused cross-attention =======================
// per block: 64 data rows. LN29 -> qproj (29->64) -> attn(256 keys) -> @Wo(64->29)+bias -> data +=
__global__ __launch_bounds__(256) void k_cattn(
    const float* __restrict__ X, const float* __restrict__ lng, const float* __restrict__ lnb,
    const unsigned short* __restrict__ WqT, const unsigned short* __restrict__ Kb,
    const unsigned short* __restrict__ Vt, const unsigned short* __restrict__ WoT,
    const float* __restrict__ bo, float* __restrict__ C, float scale)
{
  __shared__ __align__(16) unsigned short qn[64*40];
  __shared__ __align__(16) unsigned short qa[4][16*72];
  int tid = threadIdx.x, lane = tid & 63, w = tid >> 6;
  int l15 = lane & 15, g = lane >> 4;
  int r0 = blockIdx.x*64;
  int bh = r0 >> 14;                 // batch index (heads=1, 16384 rows/batch)
  // ---- LN29 into LDS (bf16, stride 40, cols 29..31 zero) ----
  if (tid < 64){
    const float* x = X + (size_t)(r0 + tid)*29;
    float a[29]; float s = 0.f;
    #pragma unroll
    for (int k=0;k<29;k++){ a[k]=x[k]; s+=a[k]; }
    float mean = s*(1.0f/29.0f);
    float qv = 0.f;
    #pragma unroll
    for (int k=0;k<29;k++){ float d=a[k]-mean; qv+=d*d; }
    float rstd = rsqrtf(qv*(1.0f/29.0f) + 1e-5f);
    unsigned short yb[32] __attribute__((aligned(16)));
    #pragma unroll
    for (int k=0;k<29;k++) yb[k] = f2bf((a[k]-mean)*rstd*lng[k] + lnb[k]);
    yb[29]=0; yb[30]=0; yb[31]=0;
    uint4* d4 = (uint4*)(qn + tid*40);
    const uint4* s4 = (const uint4*)yb;
    d4[0]=s4[0]; d4[1]=s4[1]; d4[2]=s4[2]; d4[3]=s4[3];
  }
  __syncthreads();
  // ---- q = LN(data) @ WqT : 16 rows per wave ----
  int rw = w*16;
  bf16x8 a0 = *(const bf16x8*)(qn + (rw + l15)*40 + g*8);
  f32x4 qv4[4];
  #pragma unroll
  for (int nt=0;nt<4;nt++) qv4[nt] = (f32x4){0.f,0.f,0.f,0.f};
  #pragma unroll
  for (int nt=0;nt<4;nt++){
    bf16x8 bw = *(const bf16x8*)(WqT + (size_t)(nt*16 + l15)*32 + g*8);
    qv4[nt] = __builtin_amdgcn_mfma_f32_16x16x32_bf16(a0, bw, qv4[nt], 0,0,0);
  }
  // ---- C-layout -> A-layout via per-wave LDS ----
  unsigned short* pa = qa[w];
  #pragma unroll
  for (int nt=0;nt<4;nt++)
    #pragma unroll
    for (int r=0;r<4;r++)
      pa[(g*4+r)*72 + nt*16 + l15] = f2bf(qv4[nt][r]);
  __builtin_amdgcn_wave_barrier();
  bf16x8 aq[2];
  aq[0] = *(const bf16x8*)(pa + l15*72 + g*8);
  aq[1] = *(const bf16x8*)(pa + l15*72 + 32 + g*8);
  __builtin_amdgcn_wave_barrier();
  // ---- scores ----
  const unsigned short* kbb = Kb + ((size_t)bh*256 + l15)*64 + g*8;
  f32x4 sc[16];
  #pragma unroll
  for (int nt=0;nt<16;nt++) sc[nt] = (f32x4){0.f,0.f,0.f,0.f};
  #pragma unroll
  for (int nt=0;nt<16;nt++){
    bf16x8 b0 = *(const bf16x8*)(kbb + (size_t)nt*1024);
    bf16x8 b1 = *(const bf16x8*)(kbb + (size_t)nt*1024 + 32);
    sc[nt] = __builtin_amdgcn_mfma_f32_16x16x32_bf16(aq[0], b0, sc[nt], 0,0,0);
    sc[nt] = __builtin_amdgcn_mfma_f32_16x16x32_bf16(aq[1], b1, sc[nt], 0,0,0);
  }
  // ---- softmax (rows = g*4+r, reduce across 16-lane group) ----
  float mx[4] = {-1e30f,-1e30f,-1e30f,-1e30f};
  #pragma unroll
  for (int nt=0;nt<16;nt++)
    #pragma unroll
    for (int r=0;r<4;r++){ float v = sc[nt][r]*scale; sc[nt][r]=v; mx[r]=fmaxf(mx[r],v); }
  #pragma unroll
  for (int r=0;r<4;r++){
    #pragma unroll
    for (int m=1;m<16;m<<=1) mx[r] = fmaxf(mx[r], __shfl_xor(mx[r], m));
  }
  float sum[4] = {0.f,0.f,0.f,0.f};
  #pragma unroll
  for (int nt=0;nt<16;nt++)
    #pragma unroll
    for (int r=0;r<4;r++){ float e = __expf(sc[nt][r]-mx[r]); sc[nt][r]=e; sum[r]+=e; }
  #pragma unroll
  for (int r=0;r<4;r++){
    #pragma unroll
    for (int m=1;m<16;m<<=1) sum[r] += __shfl_xor(sum[r], m);
  }
  // ---- PV (P via per-wave LDS, stride 40) ----
  f32x4 o[4];
  #pragma unroll
  for (int nd=0;nd<4;nd++) o[nd] = (f32x4){0.f,0.f,0.f,0.f};
  const unsigned short* vb = Vt + ((size_t)bh*64 + l15)*256 + g*8;
  #pragma unroll
  for (int kt=0;kt<8;kt++){
    __builtin_amdgcn_wave_barrier();
    #pragma unroll
    for (int t2=0;t2<2;t2++){
      int nt = kt*2 + t2;
      #pragma unroll
      for (int r=0;r<4;r++)
        pa[(g*4+r)*40 + t2*16 + l15] = f2bf(sc[nt][r]);
    }
    __builtin_amdgcn_wave_barrier();
    bf16x8 ap = *(const bf16x8*)(pa + l15*40 + g*8);
    #pragma unroll
    for (int nd=0;nd<4;nd++){
      bf16x8 bv = *(const bf16x8*)(vb + (size_t)nd*4096 + kt*32);
      o[nd] = __builtin_amdgcn_mfma_f32_16x16x32_bf16(ap, bv, o[nd], 0,0,0);
    }
  }
  float inv[4];
  #pragma unroll
  for (int r=0;r<4;r++) inv[r] = 1.0f/sum[r];
  // ---- attn out (bf16) -> A-layout via LDS ----
  __builtin_amdgcn_wave_barrier();
  #pragma unroll
  for (int nd=0;nd<4;nd++)
    #pragma unroll
    for (int r=0;r<4;r++)
      pa[(g*4+r)*72 + nd*16 + l15] = f2bf(o[nd][r]*inv[r]);
  __builtin_amdgcn_wave_barrier();
  bf16x8 ao0 = *(const bf16x8*)(pa + l15*72 + g*8);
  bf16x8 ao1 = *(const bf16x8*)(pa + l15*72 + 32 + g*8);
  // ---- out @ WoT (64->29) + bias, accumulate into data ----
  f32x4 c2[2];
  #pragma unroll
  for (int nt=0;nt<2;nt++) c2[nt] = (f32x4){0.f,0.f,0.f,0.f};
  #pragma unroll
  for (int nt=0;nt<2;nt++){
    bf16x8 bw0 = *(const bf16x8*)(WoT + (size_t)(nt*16 + l15)*64 + g*8);
    bf16x8 bw1 = *(const bf16x8*)(WoT + (size_t)(nt*16 + l15)*64 + 32 + g*8);
    c2[nt] = __builtin_amdgcn_mfma_f32_16x16x32_bf16(ao0, bw0, c2[nt], 0,0,0);
    c2[nt] = __builtin_amdgcn_mfma_f32_16x16x32_bf16(ao1, bw1, c2[nt], 0,0,0);
  }
  #pragma unroll
  for (int nt=0;nt<2;nt++){
    int col = nt*16 + l15;
    if (col < 29){
      #pragma unroll
      for (int r=0;r<4;r++){
        size_t off = (size_t)(r0 + rw + g*4 + r)*29 + col;
        C[off] += c2[nt][r] + bo[col];
      }
    }
  }
}

// ======================= fully fused cross FF =======================
// per block: 128 rows. LN29 -> FF1(29->256)+GEGLU -> @W2T(128->29)+bias -> data +=
__global__ __launch_bounds__(256) void k_cff(
    const float* __restrict__ X, const float* __restrict__ lng, const float* __restrict__ lnb,
    const unsigned short* __restrict__ W1rT, const float* __restrict__ b1r,
    const unsigned short* __restrict__ W2T, const float* __restrict__ b2,
    float* __restrict__ C)
{
  __shared__ __align__(16) unsigned short sm1[128*40];
  __shared__ __align__(16) unsigned short gga[4][32*136];
  int tid = threadIdx.x, lane = tid & 63, w = tid >> 6;
  int l15 = lane & 15, g = lane >> 4;
  int row0b = blockIdx.x*128;
  // ---- LN29 ----
  if (tid < 128){
    const float* x = X + (size_t)(row0b + tid)*29;
    float a[29]; float s = 0.f;
    #pragma unroll
    for (int k=0;k<29;k++){ a[k]=x[k]; s+=a[k]; }
    float mean = s*(1.0f/29.0f);
    float qv = 0.f;
    #pragma unroll
    for (int k=0;k<29;k++){ float d=a[k]-mean; qv+=d*d; }
    float rstd = rsqrtf(qv*(1.0f/29.0f) + 1e-5f);
    unsigned short yb[32] __attribute__((aligned(16)));
    #pragma unroll
    for (int k=0;k<29;k++) yb[k] = f2bf((a[k]-mean)*rstd*lng[k] + lnb[k]);
    yb[29]=0; yb[30]=0; yb[31]=0;
    uint4* d4 = (uint4*)(sm1 + tid*40);
    const uint4* s4 = (const uint4*)yb;
    d4[0]=s4[0]; d4[1]=s4[1]; d4[2]=s4[2]; d4[3]=s4[3];
  }
  __syncthreads();
  // ---- FF1 + GEGLU: 32 rows per wave ----
  int rw = w*32;
  bf16x8 a0 = *(const bf16x8*)(sm1 + (rw + l15)*40 + g*8);
  bf16x8 a1 = *(const bf16x8*)(sm1 + (rw + 16 + l15)*40 + g*8);
  f32x4 acc[2][16];
  #pragma unroll
  for (int mt=0;mt<2;mt++)
    #pragma unroll
    for (int nt=0;nt<16;nt++) acc[mt][nt] = (f32x4){0.f,0.f,0.f,0.f};
  #pragma unroll
  for (int nt=0;nt<16;nt++){
    bf16x8 bw = *(const bf16x8*)(W1rT + (size_t)(nt*16 + l15)*32 + g*8);
    acc[0][nt] = __builtin_amdgcn_mfma_f32_16x16x32_bf16(a0, bw, acc[0][nt], 0,0,0);
    acc[1][nt] = __builtin_amdgcn_mfma_f32_16x16x32_bf16(a1, bw, acc[1][nt], 0,0,0);
  }
  unsigned short* gg = gga[w];
  #pragma unroll
  for (int mt=0;mt<2;mt++){
    #pragma unroll
    for (int t=0;t<8;t++){
      float ba = b1r[t*16 + l15];
      float bg = b1r[128 + t*16 + l15];
      #pragma unroll
      for (int r=0;r<4;r++){
        float av = acc[mt][t][r]   + ba;
        float gv = acc[mt][t+8][r] + bg;
        gg[(mt*16 + g*4 + r)*136 + t*16 + l15] = f2bf(av * gelu_exact(gv));
      }
    }
  }
  __builtin_amdgcn_wave_barrier();
  // ---- gg(32x128) @ W2T(32x128)^T -> += data ----
  f32x4 c2[2][2];
  #pragma unroll
  for (int mt=0;mt<2;mt++)
    #pragma unroll
    for (int nt=0;nt<2;nt++) c2[mt][nt] = (f32x4){0.f,0.f,0.f,0.f};
  #pragma unroll
  for (int kt=0;kt<4;kt++){
    bf16x8 af0 = *(const bf16x8*)(gg + (size_t)(l15)*136 + kt*32 + g*8);
    bf16x8 af1 = *(const bf16x8*)(gg + (size_t)(16 + l15)*136 + kt*32 + g*8);
    #pragma unroll
    for (int nt=0;nt<2;nt++){
      bf16x8 bw = *(const bf16x8*)(W2T + (size_t)(nt*16 + l15)*128 + kt*32 + g*8);
      c2[0][nt] = __builtin_amdgcn_mfma_f32_16x16x32_bf16(af0, bw, c2[0][nt], 0,0,0);
      c2[1][nt] = __builtin_amdgcn_mfma_f32_16x16x32_bf16(af1, bw, c2[1][nt], 0,0,0);
    }
  }
  #pragma unroll
  for (int mt=0;mt<2;mt++)
    #pragma unroll
    for (int nt=0;nt<2;nt++){
      int col = nt*16 + l15;
      if (col < 29){
        #pragma unroll
        for (int r=0;r<4;r++){
          size_t off = (size_t)(row0b + rw + mt*16 + g*4 + r)*29 + col;
          C[off] += c2[mt][nt][r] + b2[col];
        }
      }
    }
}

// ======================= output =======================
__global__ __launch_bounds__(256) void k_out(const float* __restrict__ data, float* __restrict__ out)
{
  int idx = blockIdx.x*256 + threadIdx.x;
  int p = idx/3, c = idx - p*3;
  out[idx] = data[(size_t)p*29 + c];
}

// =====================================================================
extern "C" void kernel_launch(void* const* d_in, const int* in_sizes, int n_in,
                              void* d_out, int out_size, void* d_ws, size_t ws_size,
                              hipStream_t stream) {
  const float* x        = (const float*)d_in[0];
  const float* latents  = (const float*)d_in[1];
  const float* W_l2l    = (const float*)d_in[2];
  const float* b_l2l    = (const float*)d_in[3];
  const float* ca_ln_q_g= (const float*)d_in[4];
  const float* ca_ln_q_b= (const float*)d_in[5];
  const float* ca_ln_c_g= (const float*)d_in[6];
  const float* ca_ln_c_b= (const float*)d_in[7];
  const float* ca_Wq    = (const float*)d_in[8];
  const float* ca_Wkv   = (const float*)d_in[9];
  const float* ca_Wo    = (const float*)d_in[10];
  const float* ca_bo    = (const float*)d_in[11];
  const float* cf_ln_g  = (const float*)d_in[12];
  const float* cf_ln_b  = (const float*)d_in[13];
  const float* cf_W1    = (const float*)d_in[14];
  const float* cf_b1    = (const float*)d_in[15];
  const float* cf_W2    = (const float*)d_in[16];
  const float* cf_b2    = (const float*)d_in[17];
  const float* la_ln_g  = (const float*)d_in[18];
  const float* la_ln_b  = (const float*)d_in[19];
  const float* la_Wq    = (const float*)d_in[20];
  const float* la_Wkv   = (const float*)d_in[21];
  const float* la_Wo    = (const float*)d_in[22];
  const float* la_bo    = (const float*)d_in[23];
  const float* lf_ln_g  = (const float*)d_in[24];
  const float* lf_ln_b  = (const float*)d_in[25];
  const float* lf_W1    = (const float*)d_in[26];
  const float* lf_b1    = (const float*)d_in[27];
  const float* lf_W2    = (const float*)d_in[28];
  const float* lf_b2    = (const float*)d_in[29];

  float* ws = (float*)d_ws;
  // ---- layout (floats) ----
  float* data = ws;                                   // 3,801,088
  float* lat  = ws + 3801088;                         // 1,048,576
  unsigned short* latn_hi = (unsigned short*)(ws + 4849664); // 2048*512 hi|lo
  unsigned short* latn_lo = latn_hi + 1048576;
  float* I    = ws + 5898240;                         // 14,680,064 arena
  float* kv_c = ws + 20578304;                        // 4 x 262,144 z-partials
  unsigned short* Kb_c = (unsigned short*)(ws + 21626880);   // 131,072 ush
  unsigned short* Vt_c = Kb_c + 131072;                      // 131,072 ush
  unsigned short* wsp  = (unsigned short*)(ws + 21757952);   // 4 x LSTRIDE ush
  // arena I aliases (temporally disjoint):
  float* q_l  = I;                                      // 2048x512 f
  unsigned short* Kb_l   = (unsigned short*)(I + 3145728);  // 64*256*64
  unsigned short* Vthi_l = Kb_l + 1048576;
  unsigned short* Vtlo_l = Vthi_l + 1048576;
  unsigned short* ao_hi  = (unsigned short*)(I + 4718592);  // 2048x512 hi|lo
  unsigned short* ao_lo  = ao_hi + 1048576;
  unsigned short* gg_hi = (unsigned short*)(I + 8388608);   // 2048x2048 hi|lo
  unsigned short* gg_lo = gg_hi + 4194304;

  k_encode<<<64, 256, 0, stream>>>(data);
  k_l2l   <<<512, 256, 0, stream>>>(x, W_l2l, b_l2l, latents, lat);

  // ---- all-layer weight preps (batched over z) ----
  // combined q|kv weights: wqkvt = hi rows 0..1535, lo at +1536*512
  k_split_w<<<dim3(8,8,4),  256,0,stream>>>(la_Wq,  wsp,          512, 512, 1536, 0);
  k_split_w<<<dim3(8,16,4), 256,0,stream>>>(la_Wkv, wsp,          512,1024, 1536, 512);
  k_split_w<<<dim3(8,8,4),  256,0,stream>>>(la_Wo,  wsp+1572864,  512, 512,  512, 0);
  k_split_w<<<dim3(8,64,4), 256,0,stream>>>(lf_W1,  wsp+2097152,  512,4096, 4096, 0);
  k_split_w<<<dim3(32,8,4), 256,0,stream>>>(lf_W2,  wsp+6291456, 2048, 512,  512, 0);
  k_split_w<<<dim3(8,2,4),  256,0,stream>>>(ca_Wkv, wsp+8388608,  512, 128,  128, 0);
  k_prep_t <<<dim3(4,1,4),256,0,stream>>>(ca_Wq, wsp+8519680, 29, 64, 32, 64);
  k_prep_t <<<dim3(4,1,4),256,0,stream>>>(ca_Wo, wsp+8521728, 64, 29, 64, 32);
  k_prep_t <<<dim3(8,1,4),256,0,stream>>>(cf_W2, wsp+8523776, 116, 29, 128, 32);
  k_prep_w1<<<dim3(32,1,4),256,0,stream>>>(cf_W1, cf_b1, wsp+8527872);

  for (int i=0;i<4;i++){
    unsigned short* wl = wsp + (size_t)i*LSTRIDE;
    unsigned short* wqkvt= wl;
    unsigned short* wot  = wl + 1572864;
    unsigned short* w1t  = wl + 2097152;
    unsigned short* w2t  = wl + 6291456;
    unsigned short* cakvt= wl + 8388608;
    unsigned short* WqT  = wl + 8519680;
    unsigned short* WoT  = wl + 8521728;
    unsigned short* W2T  = wl + 8523776;
    unsigned short* W1rT = wl + 8527872;
    float* b1r = (float*)(wl + 8536064);

    // ---- latent self-attention ----
    k_ln512s<<<2048,256,0,stream>>>(lat, la_ln_g+i*512, la_ln_b+i*512, latn_hi, latn_lo);
    k_mfma_qkv<<<dim3(16,12),256,0,stream>>>(latn_hi, wqkvt, q_l, Kb_l, Vthi_l, Vtlo_l,
                                             2048, 1536, 512);
    k_attn_mf<1,1,1><<<256,256,0,stream>>>(q_l, Kb_l, Vthi_l, Vtlo_l, ao_hi, ao_lo,
                                           512, 512, 8, 256, 0.125f);
    k_mfma<<<dim3(16,4,2),256,0,stream>>>(ao_hi, wot, la_bo+i*512, lat, 2048, 512, 512, 2, 1);
    // ---- latent GEGLU FF ----
    k_ln512s<<<2048,256,0,stream>>>(lat, lf_ln_g+i*512, lf_ln_b+i*512, latn_hi, latn_lo);
    k_mfma_glu<<<dim3(16,32),256,0,stream>>>(latn_hi, w1t, lf_b1+i*4096, gg_hi, gg_lo);
    k_mfma<<<dim3(16,4,4),256,0,stream>>>(gg_hi, w2t, lf_b2+i*512, lat, 2048, 512, 2048, 4, 1);
    // ---- cross-attention (fused LN+qproj+attn+out-proj) ----
    k_ln512s<<<2048,256,0,stream>>>(lat, ca_ln_c_g+i*512, ca_ln_c_b+i*512, latn_hi, latn_lo);
    k_mfma<<<dim3(16,1,4),256,0,stream>>>(latn_hi, cakvt, nullptr, kv_c, 2048, 128, 512, 4, 0);
    k_kvprep<<<512,256,0,stream>>>(kv_c, 128, 0, 64, 1, 8, Kb_c, Vt_c, nullptr, 4, 262144);
    k_cattn<<<2048,256,0,stream>>>(data, ca_ln_q_g+i*29, ca_ln_q_b+i*29, WqT,
                                   Kb_c, Vt_c, WoT, ca_bo+i*29, data, 0.125f);
    // ---- cross GEGLU FF (fused LN+FF1+GEGLU+W2) ----
    k_cff<<<1024,256,0,stream>>>(data, cf_ln_g+i*29, cf_ln_b+i*29, W1rT, b1r,
                                 W2T, cf_b2+i*29, data);
  }

  k_out<<<1536,256,0,stream>>>(data, (float*)d_out);
}

// Round 3
// 1552.173 us; speedup vs baseline: 1.2873x; 1.2001x over previous
//
#include <hip/hip_runtime.h>
#include <math.h>

#define DEV __device__ __forceinline__
#define LSTRIDE 8537088

DEV float gelu_exact(float x){ return 0.5f*x*(1.0f+erff(x*0.70710678118654752440f)); }

DEV unsigned short f2bf(float x){
  union { float f; unsigned int u; } v; v.f = x;
  unsigned int r = v.u + 0x7FFFu + ((v.u >> 16) & 1u);
  return (unsigned short)(r >> 16);
}
DEV float bf2f(unsigned short b){ union { unsigned int u; float f; } v; v.u = ((unsigned int)b)<<16; return v.f; }
DEV void split2(float x, unsigned short& h, unsigned short& l){
  h = f2bf(x); l = f2bf(x - bf2f(h));
}

typedef __bf16 bf16x8 __attribute__((ext_vector_type(8)));
typedef float  f32x4  __attribute__((ext_vector_type(4)));

DEV void gload16(const void* g, void* lds){
  __builtin_amdgcn_global_load_lds((const __attribute__((address_space(1))) unsigned int*)g,
                                   (__attribute__((address_space(3))) unsigned int*)lds, 16, 0, 0);
}

// ======================= dev: Fourier-encode =======================
DEV void dev_encode(int bx, float* __restrict__ data, int tid)
{
  int p = bx*256 + tid;
  int hh = p >> 7, ww = p & 127;
  float y = -1.0f + hh*(2.0f/127.0f);
  float x = -1.0f + ww*(2.0f/127.0f);
  float e[26];
  #pragma unroll
  for (int i=0;i<6;i++){
    float sc = exp2f(1.0f + i*0.26438561897747245f) * 3.14159265358979323846f;
    e[i]     = sinf(y*sc);
    e[6+i]   = cosf(y*sc);
    e[13+i]  = sinf(x*sc);
    e[19+i]  = cosf(x*sc);
  }
  e[12]=y; e[25]=x;
  #pragma unroll
  for (int b=0;b<8;b++){
    float* dr = data + ((size_t)(b*16384 + p))*29;
    dr[0]=0.f; dr[1]=0.f; dr[2]=0.f;
    #pragma unroll
    for (int c=0;c<26;c++) dr[3+c]=e[c];
  }
}

// ======================= dev: lat = x @ W_l2l + b + latents =======================
DEV void dev_l2l(int bx, float* xs, const float* __restrict__ x,
    const float* __restrict__ Wl, const float* __restrict__ bl,
    const float* __restrict__ latents, float* __restrict__ lat, int tid)
{
  for (int idx=tid; idx<4096; idx+=256) xs[idx]=x[idx];
  __syncthreads();
  int nIdx = bx*256 + tid;
  float acc[8] = {0,0,0,0,0,0,0,0};
  for (int k=0;k<512;k++){
    float w = Wl[(size_t)k*131072 + nIdx];
    #pragma unroll
    for (int m=0;m<8;m++) acc[m] += xs[m*512+k]*w;
  }
  float add = bl[nIdx] + latents[nIdx];
  #pragma unroll
  for (int m=0;m<8;m++) lat[(size_t)m*131072 + nIdx] = acc[m] + add;
}

// ======================= dev: weight split+transpose =======================
DEV void dev_split_w(int bx, int by, int z, float* t, const float* __restrict__ W,
    unsigned short* __restrict__ hi, int K, int N, int Ntot, int n0off, int tid)
{
  W  += (size_t)z*K*N;
  hi += (size_t)z*LSTRIDE;
  unsigned short* lo = hi + (size_t)Ntot*K;
  int k0 = bx*64, n0 = by*64;
  #pragma unroll
  for (int i=0;i<4;i++){
    int s = tid + 256*i;
    int r = s >> 4, c4 = (s & 15)*4;
    float4 v = *(const float4*)&W[(size_t)(k0+r)*N + n0 + c4];
    t[r*65+c4+0]=v.x; t[r*65+c4+1]=v.y; t[r*65+c4+2]=v.z; t[r*65+c4+3]=v.w;
  }
  __syncthreads();
  #pragma unroll
  for (int i=0;i<4;i++){
    int s = tid + 256*i;
    int n = s >> 4, kc = (s & 15)*4;
    size_t o = (size_t)(n0off + n0 + n)*K + k0 + kc;
    #pragma unroll
    for (int j=0;j<4;j++){
      unsigned short h,l; split2(t[(kc+j)*65+n], h, l);
      hi[o+j]=h; lo[o+j]=l;
    }
  }
}

// ======================= dev: small transpose =======================
DEV void dev_prep_t(int bx, int z, int nbx, const float* __restrict__ src,
    unsigned short* __restrict__ dst, int K, int N, int Kd, int Nd, int tid)
{
  src += (size_t)z*K*N;
  dst += (size_t)z*LSTRIDE;
  for (int idx = bx*256 + tid; idx < Nd*Kd; idx += nbx*256){
    int n = idx / Kd, k = idx - n*Kd;
    float v = (k<K && n<N) ? src[(size_t)k*N + n] : 0.f;
    dst[idx] = f2bf(v);
  }
}

// ======================= dev: W1 reorder+transpose =======================
DEV void dev_prep_w1(int bx, int z, const float* __restrict__ W1,
    const float* __restrict__ b1, unsigned short* __restrict__ dst, int tid)
{
  W1  += (size_t)z*6728;
  b1  += (size_t)z*232;
  dst += (size_t)z*LSTRIDE;
  float* b1r = (float*)(dst + 8192);
  for (int idx = bx*256 + tid; idx < 256*32; idx += 32*256){
    int n = idx >> 5, k = idx & 31;
    int f = n & 127, isg = n >> 7;
    float v = 0.f;
    if (f < 116 && k < 29) v = W1[(size_t)k*232 + isg*116 + f];
    dst[idx] = f2bf(v);
  }
  int n = bx*256 + tid;
  if (n < 256){
    int f = n & 127, isg = n >> 7;
    b1r[n] = (f < 116) ? b1[isg*116 + f] : 0.f;
  }
}

// ======================= dev: split-bf16 MFMA GEMM =======================
DEV void dev_gemm(int bx, int by, int bz, unsigned short* sm,
    const unsigned short* __restrict__ Ahi, const unsigned short* __restrict__ Bhi,
    const float* __restrict__ bias, float* __restrict__ C,
    int M, int N, int K, int Ksplit, int accum, int tid)
{
  int lane = tid & 63, w = tid >> 6;
  int bm = bx*128, bn = by*128;
  int Ks = K / Ksplit;
  int kbeg = bz * Ks;
  const unsigned short* tsrc;
  if      (w==0) tsrc = Ahi + (size_t)bm*K;
  else if (w==1) tsrc = Ahi + (size_t)M*K + (size_t)bm*K;
  else if (w==2) tsrc = Bhi + (size_t)bn*K;
  else           tsrc = Bhi + (size_t)N*K + (size_t)bn*K;
  unsigned short* mylds = sm + w*4096;
  f32x4 acc[4][4];
  #pragma unroll
  for(int i=0;i<4;i++)
    #pragma unroll
    for(int j=0;j<4;j++) acc[i][j] = (f32x4){0.f,0.f,0.f,0.f};
  int wm = (w>>1)*64, wn = (w&1)*64;
  int frow = lane & 15, fq = lane >> 4;
  for (int k0 = kbeg; k0 < kbeg + Ks; k0 += 32){
    #pragma unroll
    for (int j=0;j<8;j++){
      int idx = j*64 + lane;
      int row = idx >> 2, qp = idx & 3;
      int q = (qp - row) & 3;
      gload16(tsrc + (size_t)row*K + k0 + q*8, mylds + j*512);
    }
    __syncthreads();
    bf16x8 ah[4], al[4];
    #pragma unroll
    for (int mt=0;mt<4;mt++){
      int row = wm + mt*16 + frow;
      int off = row*32 + ((fq + row)&3)*8;
      ah[mt] = *(const bf16x8*)(sm + off);
      al[mt] = *(const bf16x8*)(sm + 4096 + off);
    }
    #pragma unroll
    for (int nt=0;nt<4;nt++){
      int rowb = wn + nt*16 + frow;
      int offb = rowb*32 + ((fq + rowb)&3)*8;
      bf16x8 bh = *(const bf16x8*)(sm + 2*4096 + offb);
      bf16x8 bl = *(const bf16x8*)(sm + 3*4096 + offb);
      #pragma unroll
      for (int mt=0;mt<4;mt++){
        acc[mt][nt] = __builtin_amdgcn_mfma_f32_16x16x32_bf16(ah[mt], bh, acc[mt][nt], 0,0,0);
        acc[mt][nt] = __builtin_amdgcn_mfma_f32_16x16x32_bf16(ah[mt], bl, acc[mt][nt], 0,0,0);
        acc[mt][nt] = __builtin_amdgcn_mfma_f32_16x16x32_bf16(al[mt], bh, acc[mt][nt], 0,0,0);
      }
    }
    __syncthreads();
  }
  size_t zoff = (size_t)bz * ((size_t)M*N);
  #pragma unroll
  for (int mt=0;mt<4;mt++){
    #pragma unroll
    for (int nt=0;nt<4;nt++){
      int col = bn + wn + nt*16 + frow;
      float bv = (bias && bz==0) ? bias[col] : 0.f;
      #pragma unroll
      for (int r=0;r<4;r++){
        int row = bm + wm + mt*16 + fq*4 + r;
        float v = acc[mt][nt][r] + bv;
        if (accum) atomicAdd(&C[(size_t)row*N + col], v);
        else       C[zoff + (size_t)row*N + col] = v;
      }
    }
  }
}

// ======================= dev: fused latent QKV GEMM =======================
DEV void dev_qkv(int bx, int by, unsigned short* sm,
    const unsigned short* __restrict__ Ahi, const unsigned short* __restrict__ Bhi,
    float* __restrict__ qout, unsigned short* __restrict__ Kb,
    unsigned short* __restrict__ Vthi, unsigned short* __restrict__ Vtlo, int tid)
{
  const int M = 2048, N = 1536, K = 512;
  int lane = tid & 63, w = tid >> 6;
  int bm = bx*128, bn = by*128;
  const unsigned short* tsrc;
  if      (w==0) tsrc = Ahi + (size_t)bm*K;
  else if (w==1) tsrc = Ahi + (size_t)M*K + (size_t)bm*K;
  else if (w==2) tsrc = Bhi + (size_t)bn*K;
  else           tsrc = Bhi + (size_t)N*K + (size_t)bn*K;
  unsigned short* mylds = sm + w*4096;
  f32x4 acc[4][4];
  #pragma unroll
  for(int i=0;i<4;i++)
    #pragma unroll
    for(int j=0;j<4;j++) acc[i][j] = (f32x4){0.f,0.f,0.f,0.f};
  int wm = (w>>1)*64, wn = (w&1)*64;
  int frow = lane & 15, fq = lane >> 4;
  for (int k0 = 0; k0 < K; k0 += 32){
    #pragma unroll
    for (int j=0;j<8;j++){
      int idx = j*64 + lane;
      int row = idx >> 2, qp = idx & 3;
      int q = (qp - row) & 3;
      gload16(tsrc + (size_t)row*K + k0 + q*8, mylds + j*512);
    }
    __syncthreads();
    bf16x8 ah[4], al[4];
    #pragma unroll
    for (int mt=0;mt<4;mt++){
      int row = wm + mt*16 + frow;
      int off = row*32 + ((fq + row)&3)*8;
      ah[mt] = *(const bf16x8*)(sm + off);
      al[mt] = *(const bf16x8*)(sm + 4096 + off);
    }
    #pragma unroll
    for (int nt=0;nt<4;nt++){
      int rowb = wn + nt*16 + frow;
      int offb = rowb*32 + ((fq + rowb)&3)*8;
      bf16x8 bh = *(const bf16x8*)(sm + 2*4096 + offb);
      bf16x8 bl = *(const bf16x8*)(sm + 3*4096 + offb);
      #pragma unroll
      for (int mt=0;mt<4;mt++){
        acc[mt][nt] = __builtin_amdgcn_mfma_f32_16x16x32_bf16(ah[mt], bh, acc[mt][nt], 0,0,0);
        acc[mt][nt] = __builtin_amdgcn_mfma_f32_16x16x32_bf16(ah[mt], bl, acc[mt][nt], 0,0,0);
        acc[mt][nt] = __builtin_amdgcn_mfma_f32_16x16x32_bf16(al[mt], bh, acc[mt][nt], 0,0,0);
      }
    }
    __syncthreads();
  }
  #pragma unroll
  for (int mt=0;mt<4;mt++){
    #pragma unroll
    for (int nt=0;nt<4;nt++){
      int col = bn + wn + nt*16 + frow;
      #pragma unroll
      for (int r=0;r<4;r++){
        int row = bm + wm + mt*16 + fq*4 + r;
        float v = acc[mt][nt][r];
        int b = row >> 8, j = row & 255;
        if (col < 512){
          qout[(size_t)row*512 + col] = v;
        } else if (col < 1024){
          int kc = col - 512, h = kc >> 6, d = kc & 63;
          Kb[((size_t)((b*8+h)*256 + j))*64 + d] = f2bf(v);
        } else {
          int vc = col - 1024, h = vc >> 6, d = vc & 63;
          size_t idx = ((size_t)((b*8+h)*64 + d))*256 + j;
          unsigned short hh,ll; split2(v,hh,ll);
          Vthi[idx]=hh; Vtlo[idx]=ll;
        }
      }
    }
  }
}

// ======================= dev: latent attention (QF32, split V, split O) ============
DEV void dev_attn(int bid, unsigned short* Pw,
    const float* __restrict__ Qv, const unsigned short* __restrict__ Kb,
    const unsigned short* __restrict__ Vthi, const unsigned short* __restrict__ Vtlo,
    unsigned short* __restrict__ O0, unsigned short* __restrict__ O1,
    int q_rs, int o_rs, int heads, int nper, float scale, int tid)
{
  int lane = tid & 63, w = tid >> 6;
  int l15 = lane & 15, g = lane >> 4;
  int bpb = nper >> 6;
  int bh = bid / bpb;
  int q0 = (bid - bh*bpb)*64 + w*16;
  int b = bh / heads, h = bh - b*heads;
  bf16x8 aq[2];
  int qrow = b*nper + q0 + l15;
  const float* qp = Qv + (size_t)qrow*q_rs + h*64 + g*8;
  #pragma unroll
  for (int kt=0;kt<2;kt++){
    bf16x8 v;
    #pragma unroll
    for (int j=0;j<8;j++) v[j] = (__bf16)qp[kt*32 + j];
    aq[kt]=v;
  }
  const unsigned short* kbb = Kb + ((size_t)bh*256 + l15)*64 + g*8;
  f32x4 sc[16];
  #pragma unroll
  for (int nt=0;nt<16;nt++) sc[nt] = (f32x4){0.f,0.f,0.f,0.f};
  #pragma unroll
  for (int nt=0;nt<16;nt++){
    bf16x8 b0 = *(const bf16x8*)(kbb + (size_t)nt*1024);
    bf16x8 b1 = *(const bf16x8*)(kbb + (size_t)nt*1024 + 32);
    sc[nt] = __builtin_amdgcn_mfma_f32_16x16x32_bf16(aq[0], b0, sc[nt], 0,0,0);
    sc[nt] = __builtin_amdgcn_mfma_f32_16x16x32_bf16(aq[1], b1, sc[nt], 0,0,0);
  }
  float mx[4] = {-1e30f,-1e30f,-1e30f,-1e30f};
  #pragma unroll
  for (int nt=0;nt<16;nt++)
    #pragma unroll
    for (int r=0;r<4;r++){ float v = sc[nt][r]*scale; sc[nt][r]=v; mx[r]=fmaxf(mx[r],v); }
  #pragma unroll
  for (int r=0;r<4;r++){
    #pragma unroll
    for (int m=1;m<16;m<<=1) mx[r] = fmaxf(mx[r], __shfl_xor(mx[r], m));
  }
  float sum[4] = {0.f,0.f,0.f,0.f};
  #pragma unroll
  for (int nt=0;nt<16;nt++)
    #pragma unroll
    for (int r=0;r<4;r++){ float e = __expf(sc[nt][r]-mx[r]); sc[nt][r]=e; sum[r]+=e; }
  #pragma unroll
  for (int r=0;r<4;r++){
    #pragma unroll
    for (int m=1;m<16;m<<=1) sum[r] += __shfl_xor(sum[r], m);
  }
  f32x4 o[4];
  #pragma unroll
  for (int nd=0;nd<4;nd++) o[nd] = (f32x4){0.f,0.f,0.f,0.f};
  unsigned short* pw = Pw + w*640;
  const unsigned short* vb  = Vthi + ((size_t)bh*64 + l15)*256 + g*8;
  const unsigned short* vbl = Vtlo + ((size_t)bh*64 + l15)*256 + g*8;
  #pragma unroll
  for (int kt=0;kt<8;kt++){
    __builtin_amdgcn_wave_barrier();
    #pragma unroll
    for (int t2=0;t2<2;t2++){
      int nt = kt*2 + t2;
      #pragma unroll
      for (int r=0;r<4;r++)
        pw[(g*4+r)*40 + t2*16 + l15] = f2bf(sc[nt][r]);
    }
    __builtin_amdgcn_wave_barrier();
    bf16x8 ap = *(const bf16x8*)(pw + l15*40 + g*8);
    #pragma unroll
    for (int nd=0;nd<4;nd++){
      bf16x8 bv = *(const bf16x8*)(vb + (size_t)nd*4096 + kt*32);
      o[nd] = __builtin_amdgcn_mfma_f32_16x16x32_bf16(ap, bv, o[nd], 0,0,0);
      bf16x8 bl = *(const bf16x8*)(vbl + (size_t)nd*4096 + kt*32);
      o[nd] = __builtin_amdgcn_mfma_f32_16x16x32_bf16(ap, bl, o[nd], 0,0,0);
    }
  }
  float inv[4];
  #pragma unroll
  for (int r=0;r<4;r++) inv[r] = 1.0f/sum[r];
  int orow0 = b*nper + q0;
  #pragma unroll
  for (int nd=0;nd<4;nd++){
    #pragma unroll
    for (int r=0;r<4;r++){
      float v = o[nd][r]*inv[r];
      size_t off = (size_t)(orow0 + g*4 + r)*o_rs + h*64 + nd*16 + l15;
      unsigned short hh,ll; split2(v,hh,ll); O0[off]=hh; O1[off]=ll;
    }
  }
}

// ======================= dev: cross KV prep (z-partials summed) =======================
DEV void dev_kvprep(int bid, int nb, const float* __restrict__ kv, int ld,
    int koff, int voff, int heads, int BH,
    unsigned short* __restrict__ Kb, unsigned short* __restrict__ Vthi,
    int zparts, int zstride, int tid)
{
  int total = BH << 14;
  for (int idx = bid*256 + tid; idx < total; idx += nb*256){
    int d = idx & 63, j = (idx>>6) & 255, bh = idx >> 14;
    int b = bh / heads, h = bh - b*heads;
    size_t base = ((size_t)(b*256 + j))*ld + koff + h*64 + d;
    float v = 0.f;
    for (int z=0; z<zparts; z++) v += kv[(size_t)z*zstride + base];
    Kb[idx] = f2bf(v);
  }
  for (int idx = bid*256 + tid; idx < total; idx += nb*256){
    int j = idx & 255, d = (idx>>8) & 63, bh = idx >> 14;
    int b = bh / heads, h = bh - b*heads;
    size_t base = ((size_t)(b*256 + j))*ld + voff + h*64 + d;
    float v = 0.f;
    for (int z=0; z<zparts; z++) v += kv[(size_t)z*zstride + base];
    Vthi[idx] = f2bf(v);
  }
}

// ======================= dev: fully fused cross-attention =======================
DEV void dev_cattn(int bid, unsigned short* smb,
    const float* __restrict__ X, const float* __restrict__ lng, const float* __restrict__ lnb,
    const unsigned short* __restrict__ WqT, const unsigned short* __restrict__ Kb,
    const unsigned short* __restrict__ Vt, const unsigned short* __restrict__ WoT,
    const float* __restrict__ bo, float* __restrict__ C, float scale, int tid)
{
  unsigned short* qn = smb;              // 64*40
  unsigned short* qa = smb + 2560;       // 4 x 16*72
  int lane = tid & 63, w = tid >> 6;
  int l15 = lane & 15, g = lane >> 4;
  int r0 = bid*64;
  int bh = r0 >> 14;
  if (tid < 64){
    const float* x = X + (size_t)(r0 + tid)*29;
    float a[29]; float s = 0.f;
    #pragma unroll
    for (int k=0;k<29;k++){ a[k]=x[k]; s+=a[k]; }
    float mean = s*(1.0f/29.0f);
    float qv = 0.f;
    #pragma unroll
    for (int k=0;k<29;k++){ float d=a[k]-mean; qv+=d*d; }
    float rstd = rsqrtf(qv*(1.0f/29.0f) + 1e-5f);
    unsigned short yb[32] __attribute__((aligned(16)));
    #pragma unroll
    for (int k=0;k<29;k++) yb[k] = f2bf((a[k]-mean)*rstd*lng[k] + lnb[k]);
    yb[29]=0; yb[30]=0; yb[31]=0;
    uint4* d4 = (uint4*)(qn + tid*40);
    const uint4* s4 = (const uint4*)yb;
    d4[0]=s4[0]; d4[1]=s4[1]; d4[2]=s4[2]; d4[3]=s4[3];
  }
  __syncthreads();
  int rw = w*16;
  bf16x8 a0 = *(const bf16x8*)(qn + (rw + l15)*40 + g*8);
  f32x4 qv4[4];
  #pragma unroll
  for (int nt=0;nt<4;nt++) qv4[nt] = (f32x4){0.f,0.f,0.f,0.f};
  #pragma unroll
  for (int nt=0;nt<4;nt++){
    bf16x8 bw = *(const bf16x8*)(WqT + (size_t)(nt*16 + l15)*32 + g*8);
    qv4[nt] = __builtin_amdgcn_mfma_f32_16x16x32_bf16(a0, bw, qv4[nt], 0,0,0);
  }
  unsigned short* pa = qa + w*1152;
  #pragma unroll
  for (int nt=0;nt<4;nt++)
    #pragma unroll
    for (int r=0;r<4;r++)
      pa[(g*4+r)*72 + nt*16 + l15] = f2bf(qv4[nt][r]);
  __builtin_amdgcn_wave_barrier();
  bf16x8 aq[2];
  aq[0] = *(const bf16x8*)(pa + l15*72 + g*8);
  aq[1] = *(const bf16x8*)(pa + l15*72 + 32 + g*8);
  __builtin_amdgcn_wave_barrier();
  const unsigned short* kbb = Kb + ((size_t)bh*256 + l15)*64 + g*8;
  f32x4 sc[16];
  #pragma unroll
  for (int nt=0;nt<16;nt++) sc[nt] = (f32x4){0.f,0.f,0.f,0.f};
  #pragma unroll
  for (int nt=0;nt<16;nt++){
    bf16x8 b0 = *(const bf16x8*)(kbb + (size_t)nt*1024);
    bf16x8 b1 = *(const bf16x8*)(kbb + (size_t)nt*1024 + 32);
    sc[nt] = __builtin_amdgcn_mfma_f32_16x16x32_bf16(aq[0], b0, sc[nt], 0,0,0);
    sc[nt] = __builtin_amdgcn_mfma_f32_16x16x32_bf16(aq[1], b1, sc[nt], 0,0,0);
  }
  float mx[4] = {-1e30f,-1e30f,-1e30f,-1e30f};
  #pragma unroll
  for (int nt=0;nt<16;nt++)
    #pragma unroll
    for (int r=0;r<4;r++){ float v = sc[nt][r]*scale; sc[nt][r]=v; mx[r]=fmaxf(mx[r],v); }
  #pragma unroll
  for (int r=0;r<4;r++){
    #pragma unroll
    for (int m=1;m<16;m<<=1) mx[r] = fmaxf(mx[r], __shfl_xor(mx[r], m));
  }
  float sum[4] = {0.f,0.f,0.f,0.f};
  #pragma unroll
  for (int nt=0;nt<16;nt++)
    #pragma unroll
    for (int r=0;r<4;r++){ float e = __expf(sc[nt][r]-mx[r]); sc[nt][r]=e; sum[r]+=e; }
  #pragma unroll
  for (int r=0;r<4;r++){
    #pragma unroll
    for (int m=1;m<16;m<<=1) sum[r] += __shfl_xor(sum[r], m);
  }
  f32x4 o[4];
  #pragma unroll
  for (int nd=0;nd<4;nd++) o[nd] = (f32x4){0.f,0.f,0.f,0.f};
  const unsigned short* vb = Vt + ((size_t)bh*64 + l15)*256 + g*8;
  #pragma unroll
  for (int kt=0;kt<8;kt++){
    __builtin_amdgcn_wave_barrier();
    #pragma unroll
    for (int t2=0;t2<2;t2++){
      int nt = kt*2 + t2;
      #pragma unroll
      for (int r=0;r<4;r++)
        pa[(g*4+r)*40 + t2*16 + l15] = f2bf(sc[nt][r]);
    }
    __builtin_amdgcn_wave_barrier();
    bf16x8 ap = *(const bf16x8*)(pa + l15*40 + g*8);
    #pragma unroll
    for (int nd=0;nd<4;nd++){
      bf16x8 bv = *(const bf16x8*)(vb + (size_t)nd*4096 + kt*32);
      o[nd] = __builtin_amdgcn_mfma_f32_16x16x32_bf16(ap, bv, o[nd], 0,0,0);
    }
  }
  float inv[4];
  #pragma unroll
  for (int r=0;r<4;r++) inv[r] = 1.0f/sum[r];
  __builtin_amdgcn_wave_barrier();
  #pragma unroll
  for (int nd=0;nd<4;nd++)
    #pragma unroll
    for (int r=0;r<4;r++)
      pa[(g*4+r)*72 + nd*16 + l15] = f2bf(o[nd][r]*inv[r]);
  __builtin_amdgcn_wave_barrier();
  bf16x8 ao0 = *(const bf16x8*)(pa + l15*72 + g*8);
  bf16x8 ao1 = *(const bf16x8*)(pa + l15*72 + 32 + g*8);
  f32x4 c2[2];
  #pragma unroll
  for (int nt=0;nt<2;nt++) c2[nt] = (f32x4){0.f,0.f,0.f,0.f};
  #pragma unroll
  for (int nt=0;nt<2;nt++){
    bf16x8 bw0 = *(const bf16x8*)(WoT + (size_t)(nt*16 + l15)*64 + g*8);
    bf16x8 bw1 = *(const bf16x8*)(WoT + (size_t)(nt*16 + l15)*64 + 32 + g*8);
    c2[nt] = __builtin_amdgcn_mfma_f32_16x16x32_bf16(ao0, bw0, c2[nt], 0,0,0);
    c2[nt] = __builtin_amdgcn_mfma_f32_16x16x32_bf16(ao1, bw1, c2[nt], 0,0,0);
  }
  #pragma unroll
  for (int nt=0;nt<2;nt++){
    int col = nt*16 + l15;
    if (col < 29){
      #pragma unroll
      for (int r=0;r<4;r++){
        size_t off = (size_t)(r0 + rw + g*4 + r)*29 + col;
        C[off] += c2[nt][r] + bo[col];
      }
    }
  }
}

// ======================= dev: fully fused cross FF =======================
DEV void dev_cff(int bid, unsigned short* smb,
    const float* __restrict__ X, const float* __restrict__ lng, const float* __restrict__ lnb,
    const unsigned short* __restrict__ W1rT, const float* __restrict__ b1r,
    const unsigned short* __restrict__ W2T, const float* __restrict__ b2,
    float* __restrict__ C, int tid)
{
  unsigned short* sm1 = smb;             // 128*40
  unsigned short* gga = smb + 5120;      // 4 x 32*136
  int lane = tid & 63, w = tid >> 6;
  int l15 = lane & 15, g = lane >> 4;
  int row0b = bid*128;
  if (tid < 128){
    const float* x = X + (size_t)(row0b + tid)*29;
    float a[29]; float s = 0.f;
    #pragma unroll
    for (int k=0;k<29;k++){ a[k]=x[k]; s+=a[k]; }
    float mean = s*(1.0f/29.0f);
    float qv = 0.f;
    #pragma unroll
    for (int k=0;k<29;k++){ float d=a[k]-mean; qv+=d*d; }
    float rstd = rsqrtf(qv*(1.0f/29.0f) + 1e-5f);
    unsigned short yb[32] __attribute__((aligned(16)));
    #pragma unroll
    for (int k=0;k<29;k++) yb[k] = f2bf((a[k]-mean)*rstd*lng[k] + lnb[k]);
    yb[29]=0; yb[30]=0; yb[31]=0;
    uint4* d4 = (uint4*)(sm1 + tid*40);
    const uint4* s4 = (const uint4*)yb;
    d4[0]=s4[0]; d4[1]=s4[1]; d4[2]=s4[2]; d4[3]=s4[3];
  }
  __syncthreads();
  int rw = w*32;
  bf16x8 a0 = *(const bf16x8*)(sm1 + (rw + l15)*40 + g*8);
  bf16x8 a1 = *(const bf16x8*)(sm1 + (rw + 16 + l15)*40 + g*8);
  f32x4 acc[2][16];
  #pragma unroll
  for (int mt=0;mt<2;mt++)
    #pragma unroll
    for (int nt=0;nt<16;nt++) acc[mt][nt] = (f32x4){0.f,0.f,0.f,0.f};
  #pragma unroll
  for (int nt=0;nt<16;nt++){
    bf16x8 bw = *(const bf16x8*)(W1rT + (size_t)(nt*16 + l15)*32 + g*8);
    acc[0][nt] = __builtin_amdgcn_mfma_f32_16x16x32_bf16(a0, bw, acc[0][nt], 0,0,0);
    acc[1][nt] = __builtin_amdgcn_mfma_f32_16x16x32_bf16(a1, bw, acc[1][nt], 0,0,0);
  }
  unsigned short* gg = gga + w*4352;
  #pragma unroll
  for (int mt=0;mt<2;mt++){
    #pragma unroll
    for (int t=0;t<8;t++){
      float ba = b1r[t*16 + l15];
      float bg = b1r[128 + t*16 + l15];
      #pragma unroll
      for (int r=0;r<4;r++){
        float av = acc[mt][t][r]   + ba;
        float gv = acc[mt][t+8][r] + bg;
        gg[(mt*16 + g*4 + r)*136 + t*16 + l15] = f2bf(av * gelu_exact(gv));
      }
    }
  }
  __builtin_amdgcn_wave_barrier();
  f32x4 c2[2][2];
  #pragma unroll
  for (int mt=0;mt<2;mt++)
    #pragma unroll
    for (int nt=0;nt<2;nt++) c2[mt][nt] = (f32x4){0.f,0.f,0.f,0.f};
  #pragma unroll
  for (int kt=0;kt<4;kt++){
    bf16x8 af0 = *(const bf16x8*)(gg + (size_t)(l15)*136 + kt*32 + g*8);
    bf16x8 af1 = *(const bf16x8*)(gg + (size_t)(16 + l15)*136 + kt*32 + g*8);
    #pragma unroll
    for (int nt=0;nt<2;nt++){
      bf16x8 bw = *(const bf16x8*)(W2T + (size_t)(nt*16 + l15)*128 + kt*32 + g*8);
      c2[0][nt] = __builtin_amdgcn_mfma_f32_16x16x32_bf16(af0, bw, c2[0][nt], 0,0,0);
      c2[1][nt] = __builtin_amdgcn_mfma_f32_16x16x32_bf16(af1, bw, c2[1][nt], 0,0,0);
    }
  }
  #pragma unroll
  for (int mt=0;mt<2;mt++)
    #pragma unroll
    for (int nt=0;nt<2;nt++){
      int col = nt*16 + l15;
      if (col < 29){
        #pragma unroll
        for (int r=0;r<4;r++){
          size_t off = (size_t)(row0b + rw + mt*16 + g*4 + r)*29 + col;
          C[off] += c2[mt][nt][r] + b2[col];
        }
      }
    }
}

// ======================= dev: wave-per-row LayerNorm 512 =======================
DEV void ln512_stats(const float* __restrict__ X, int row, int lane, float a[8],
                     float& mean, float& rstd)
{
  const float* x = X + (size_t)row*512 + lane*8;
  float4 v0 = *(const float4*)x;
  float4 v1 = *(const float4*)(x+4);
  a[0]=v0.x; a[1]=v0.y; a[2]=v0.z; a[3]=v0.w;
  a[4]=v1.x; a[5]=v1.y; a[6]=v1.z; a[7]=v1.w;
  float s = (a[0]+a[1])+(a[2]+a[3])+((a[4]+a[5])+(a[6]+a[7]));
  #pragma unroll
  for (int off=32; off; off>>=1) s += __shfl_xor(s, off);
  mean = s * (1.0f/512.0f);
  float q = 0.f;
  #pragma unroll
  for (int j=0;j<8;j++){ float d=a[j]-mean; q += d*d; }
  #pragma unroll
  for (int off=32; off; off>>=1) q += __shfl_xor(q, off);
  rstd = rsqrtf(q*(1.0f/512.0f) + 1e-5f);
}
DEV void ln512_apply(const float a[8], float mean, float rstd,
    const float* __restrict__ g, const float* __restrict__ bv, int row, int lane,
    unsigned short* __restrict__ hi, unsigned short* __restrict__ lo)
{
  const float* gp = g + lane*8; const float* bp = bv + lane*8;
  float4 g0=*(const float4*)gp, g1=*(const float4*)(gp+4);
  float4 b0=*(const float4*)bp, b1=*(const float4*)(bp+4);
  float gg[8]={g0.x,g0.y,g0.z,g0.w,g1.x,g1.y,g1.z,g1.w};
  float bb[8]={b0.x,b0.y,b0.z,b0.w,b1.x,b1.y,b1.z,b1.w};
  unsigned short hb[8] __attribute__((aligned(16)));
  unsigned short lb[8] __attribute__((aligned(16)));
  #pragma unroll
  for (int j=0;j<8;j++){
    unsigned short h,l; split2((a[j]-mean)*rstd*gg[j]+bb[j],h,l);
    hb[j]=h; lb[j]=l;
  }
  *(uint4*)(hi + (size_t)row*512 + lane*8) = *(const uint4*)hb;
  *(uint4*)(lo + (size_t)row*512 + lane*8) = *(const uint4*)lb;
}
DEV void dev_ln512w(int bid, const float* __restrict__ X,
    const float* __restrict__ g, const float* __restrict__ bv,
    unsigned short* __restrict__ hi, unsigned short* __restrict__ lo, int tid)
{
  int w = tid>>6, lane = tid&63;
  int row = bid*4 + w;
  float a[8], mean, rstd;
  ln512_stats(X, row, lane, a, mean, rstd);
  ln512_apply(a, mean, rstd, g, bv, row, lane, hi, lo);
}

// ======================= global kernels =======================
__global__ __launch_bounds__(256) void k_prep_all(
    const float* __restrict__ x, const float* __restrict__ Wl, const float* __restrict__ bl,
    const float* __restrict__ latents, float* __restrict__ lat, float* __restrict__ data,
    const float* __restrict__ la_Wq, const float* __restrict__ la_Wkv, const float* __restrict__ la_Wo,
    const float* __restrict__ lf_W1, const float* __restrict__ lf_W2, const float* __restrict__ ca_Wkv,
    const float* __restrict__ ca_Wq, const float* __restrict__ ca_Wo, const float* __restrict__ cf_W2,
    const float* __restrict__ cf_W1, const float* __restrict__ cf_b1,
    unsigned short* __restrict__ wsp)
{
  __shared__ __align__(16) float smf[4160];
  int b = blockIdx.x, tid = threadIdx.x;
  if (b < 512){ dev_l2l(b, smf, x, Wl, bl, latents, lat, tid); return; }
  b -= 512;
  if (b < 2048){ dev_split_w(b%8, (b/8)%64, b/512, smf, lf_W1, wsp+2097152, 512,4096,4096,0, tid); return; }
  b -= 2048;
  if (b < 1024){ dev_split_w(b%32, (b/32)%8, b/256, smf, lf_W2, wsp+6291456, 2048,512,512,0, tid); return; }
  b -= 1024;
  if (b < 512){ dev_split_w(b%8, (b/8)%16, b/128, smf, la_Wkv, wsp, 512,1024,1536,512, tid); return; }
  b -= 512;
  if (b < 256){ dev_split_w(b%8, (b/8)%8, b/64, smf, la_Wq, wsp, 512,512,1536,0, tid); return; }
  b -= 256;
  if (b < 256){ dev_split_w(b%8, (b/8)%8, b/64, smf, la_Wo, wsp+1572864, 512,512,512,0, tid); return; }
  b -= 256;
  if (b < 64){ dev_encode(b, data, tid); return; }
  b -= 64;
  if (b < 64){ dev_split_w(b%8, (b/8)%2, b/16, smf, ca_Wkv, wsp+8388608, 512,128,128,0, tid); return; }
  b -= 64;
  if (b < 128){ dev_prep_w1(b%32, b/32, cf_W1, cf_b1, wsp+8527872, tid); return; }
  b -= 128;
  if (b < 16){ dev_prep_t(b%4, b/4, 4, ca_Wq, wsp+8519680, 29,64,32,64, tid); return; }
  b -= 16;
  if (b < 16){ dev_prep_t(b%4, b/4, 4, ca_Wo, wsp+8521728, 64,29,64,32, tid); return; }
  b -= 16;
  dev_prep_t(b%8, b/8, 8, cf_W2, wsp+8523776, 116,29,128,32, tid);
}

__global__ __launch_bounds__(256) void k_ln512w(const float* __restrict__ X,
    const float* __restrict__ g, const float* __restrict__ bv,
    unsigned short* __restrict__ hi, unsigned short* __restrict__ lo)
{
  dev_ln512w(blockIdx.x, X, g, bv, hi, lo, threadIdx.x);
}

__global__ __launch_bounds__(256) void k_ln512d(const float* __restrict__ X,
    const float* __restrict__ g1, const float* __restrict__ b1v,
    unsigned short* __restrict__ h1, unsigned short* __restrict__ l1,
    const float* __restrict__ g2, const float* __restrict__ b2v,
    unsigned short* __restrict__ h2, unsigned short* __restrict__ l2)
{
  int tid = threadIdx.x, w = tid>>6, lane = tid&63;
  int row = blockIdx.x*4 + w;
  float a[8], mean, rstd;
  ln512_stats(X, row, lane, a, mean, rstd);
  ln512_apply(a, mean, rstd, g1, b1v, row, lane, h1, l1);
  ln512_apply(a, mean, rstd, g2, b2v, row, lane, h2, l2);
}

__global__ __launch_bounds__(256) void k_combo1(
    const unsigned short* __restrict__ Aq, const unsigned short* __restrict__ Wqkv,
    float* __restrict__ q_l, unsigned short* __restrict__ Kb_l,
    unsigned short* __restrict__ Vthi_l, unsigned short* __restrict__ Vtlo_l,
    const unsigned short* __restrict__ Ac, const unsigned short* __restrict__ Wckv,
    float* __restrict__ kv_c, int nA)
{
  __shared__ __align__(16) unsigned short sm[16384];
  int b = blockIdx.x, tid = threadIdx.x;
  if (b < nA) dev_qkv(b%16, b/16, sm, Aq, Wqkv, q_l, Kb_l, Vthi_l, Vtlo_l, tid);
  else { int c = b - nA; dev_gemm(c%16, 0, c/16, sm, Ac, Wckv, nullptr, kv_c, 2048,128,512,4,0, tid); }
}

__global__ __launch_bounds__(256) void k_combo2(
    const float* __restrict__ q_l, const unsigned short* __restrict__ Kb_l,
    const unsigned short* __restrict__ Vthi_l, const unsigned short* __restrict__ Vtlo_l,
    unsigned short* __restrict__ ao_hi, unsigned short* __restrict__ ao_lo,
    const float* __restrict__ kv_c, unsigned short* __restrict__ Kb_c,
    unsigned short* __restrict__ Vt_c, int nA, int nB)
{
  __shared__ __align__(16) unsigned short Pw[2560];
  int b = blockIdx.x, tid = threadIdx.x;
  if (b < nA) dev_attn(b, Pw, q_l, Kb_l, Vthi_l, Vtlo_l, ao_hi, ao_lo, 512, 512, 8, 256, 0.125f, tid);
  else dev_kvprep(b - nA, nB, kv_c, 128, 0, 64, 1, 8, Kb_c, Vt_c, 4, 262144, tid);
}

__global__ __launch_bounds__(256) void k_combo3(
    const unsigned short* __restrict__ ao_hi, const unsigned short* __restrict__ wot,
    const float* __restrict__ bo_l, float* __restrict__ lat,
    float* __restrict__ data, const float* __restrict__ lng, const float* __restrict__ lnb,
    const unsigned short* __restrict__ WqT, const unsigned short* __restrict__ Kb_c,
    const unsigned short* __restrict__ Vt_c, const unsigned short* __restrict__ WoT,
    const float* __restrict__ bo_c, int nA)
{
  __shared__ __align__(16) unsigned short sm[16384];
  int b = blockIdx.x, tid = threadIdx.x;
  if (b < nA) dev_gemm(b%16, (b/16)%4, b/64, sm, ao_hi, wot, bo_l, lat, 2048,512,512,2,1, tid);
  else dev_cattn(b - nA, sm, data, lng, lnb, WqT, Kb_c, Vt_c, WoT, bo_c, data, 0.125f, tid);
}

__global__ __launch_bounds__(256) void k_combo4(
    float* __restrict__ data, const float* __restrict__ cf_g, const float* __restrict__ cf_b,
    const unsigned short* __restrict__ W1rT, const float* __restrict__ b1r,
    const unsigned short* __restrict__ W2T, const float* __restrict__ b2c,
    const float* __restrict__ lat, const float* __restrict__ lf_g, const float* __restrict__ lf_b,
    unsigned short* __restrict__ lnf_hi, unsigned short* __restrict__ lnf_lo, int nA)
{
  __shared__ __align__(16) unsigned short sm[22528];
  int b = blockIdx.x, tid = threadIdx.x;
  if (b < nA) dev_cff(b, sm, data, cf_g, cf_b, W1rT, b1r, W2T, b2c, data, tid);
  else dev_ln512w(b - nA, lat, lf_g, lf_b, lnf_hi, lnf_lo, tid);
}

__global__ __launch_bounds__(256) void k_mfma(
    const unsigned short* __restrict__ Ahi, const unsigned short* __restrict__ Bhi,
    const float* __restrict__ bias, float* __restrict__ C,
    int M, int N, int K, int Ksplit, int accum)
{
  __shared__ __align__(16) unsigned short sm[16384];
  dev_gemm(blockIdx.x, blockIdx.y, blockIdx.z, sm, Ahi, Bhi, bias, C, M, N, K, Ksplit, accum, threadIdx.x);
}

// ======================= fused latent FF1 + GEGLU =======================
__global__ __launch_bounds__(256) void k_mfma_glu(
    const unsigned short* __restrict__ Ahi, const unsigned short* __restrict__ Whi,
    const float* __restrict__ b1, unsigned short* __restrict__ Ghi,
    unsigned short* __restrict__ Glo)
{
  __shared__ __align__(16) unsigned short sm[16384];
  int tid = threadIdx.x, lane = tid & 63, w = tid >> 6;
  int bm = blockIdx.x*128, bnp = blockIdx.y*64;
  const unsigned short* Alo = Ahi + (size_t)2048*512;
  const unsigned short* Wlo = Whi + (size_t)4096*512;
  f32x4 aa[4][2], ag[4][2];
  #pragma unroll
  for (int i=0;i<4;i++)
    #pragma unroll
    for (int j=0;j<2;j++){ aa[i][j]=(f32x4){0.f,0.f,0.f,0.f}; ag[i][j]=(f32x4){0.f,0.f,0.f,0.f}; }
  int wm = (w>>1)*64, wnp = (w&1)*32;
  int frow = lane & 15, fq = lane >> 4;
  for (int k0=0;k0<512;k0+=32){
    #pragma unroll
    for (int j=0;j<8;j++){
      int c0 = w*512 + j*64;
      int c  = c0 + lane;
      int sel = c0 >> 8;
      const unsigned short* src; int wi;
      if (sel < 4){
        src = (sel < 2 ? Ahi : Alo) + (size_t)bm*512;
        wi = c & 511;
      } else {
        const unsigned short* wb = (sel < 6) ? Whi : Wlo;
        int cb = bnp + ((sel & 1) ? 2048 : 0);
        src = wb + (size_t)cb*512;
        wi = c & 255;
      }
      int row = wi >> 2, qp = wi & 3;
      int q = (qp - row) & 3;
      gload16(src + (size_t)row*512 + k0 + q*8, sm + c0*8);
    }
    __syncthreads();
    bf16x8 ah[4], al[4];
    #pragma unroll
    for (int mt=0;mt<4;mt++){
      int r = wm + mt*16 + frow;
      int off = r*32 + ((fq + r)&3)*8;
      ah[mt] = *(const bf16x8*)(sm + off);
      al[mt] = *(const bf16x8*)(sm + 4096 + off);
    }
    #pragma unroll
    for (int nt=0;nt<2;nt++){
      int rb = wnp + nt*16 + frow;
      int offb = rb*32 + ((fq + rb)&3)*8;
      bf16x8 bah = *(const bf16x8*)(sm +  8192 + offb);
      bf16x8 bgh = *(const bf16x8*)(sm + 10240 + offb);
      bf16x8 bal = *(const bf16x8*)(sm + 12288 + offb);
      bf16x8 bgl = *(const bf16x8*)(sm + 14336 + offb);
      #pragma unroll
      for (int mt=0;mt<4;mt++){
        aa[mt][nt] = __builtin_amdgcn_mfma_f32_16x16x32_bf16(ah[mt], bah, aa[mt][nt], 0,0,0);
        aa[mt][nt] = __builtin_amdgcn_mfma_f32_16x16x32_bf16(ah[mt], bal, aa[mt][nt], 0,0,0);
        aa[mt][nt] = __builtin_amdgcn_mfma_f32_16x16x32_bf16(al[mt], bah, aa[mt][nt], 0,0,0);
        ag[mt][nt] = __builtin_amdgcn_mfma_f32_16x16x32_bf16(ah[mt], bgh, ag[mt][nt], 0,0,0);
        ag[mt][nt] = __builtin_amdgcn_mfma_f32_16x16x32_bf16(ah[mt], bgl, ag[mt][nt], 0,0,0);
        ag[mt][nt] = __builtin_amdgcn_mfma_f32_16x16x32_bf16(al[mt], bgh, ag[mt][nt], 0,0,0);
      }
    }
    __syncthreads();
  }
  #pragma unroll
  for (int mt=0;mt<4;mt++){
    #pragma unroll
    for (int nt=0;nt<2;nt++){
      int col = bnp + wnp + nt*16 + frow;
      float ba = b1[col], bg = b1[2048+col];
      #pragma unroll
      for (int r=0;r<4;r++){
        int row = bm + wm + mt*16 + fq*4 + r;
        float av = aa[mt][nt][r] + ba;
        float gv = ag[mt][nt][r] + bg;
        unsigned short h,l; split2(av*gelu_exact(gv), h, l);
        Ghi[(size_t)row*2048 + col] = h;
        Glo[(size_t)row*2048 + col] = l;
      }
    }
  }
}

// ======================= output =======================
__global__ __launch_bounds__(256) void k_out(const float* __restrict__ data, float* __restrict__ out)
{
  int idx = blockIdx.x*256 + threadIdx.x;
  int p = idx/3, c = idx - p*3;
  out[idx] = data[(size_t)p*29 + c];
}

// =====================================================================
extern "C" void kernel_launch(void* const* d_in, const int* in_sizes, int n_in,
                              void* d_out, int out_size, void* d_ws, size_t ws_size,
                              hipStream_t stream) {
  const float* x        = (const float*)d_in[0];
  const float* latents  = (const float*)d_in[1];
  const float* W_l2l    = (const float*)d_in[2];
  const float* b_l2l    = (const float*)d_in[3];
  const float* ca_ln_q_g= (const float*)d_in[4];
  const float* ca_ln_q_b= (const float*)d_in[5];
  const float* ca_ln_c_g= (const float*)d_in[6];
  const float* ca_ln_c_b= (const float*)d_in[7];
  const float* ca_Wq    = (const float*)d_in[8];
  const float* ca_Wkv   = (const float*)d_in[9];
  const float* ca_Wo    = (const float*)d_in[10];
  const float* ca_bo    = (const float*)d_in[11];
  const float* cf_ln_g  = (const float*)d_in[12];
  const float* cf_ln_b  = (const float*)d_in[13];
  const float* cf_W1    = (const float*)d_in[14];
  const float* cf_b1    = (const float*)d_in[15];
  const float* cf_W2    = (const float*)d_in[16];
  const float* cf_b2    = (const float*)d_in[17];
  const float* la_ln_g  = (const float*)d_in[18];
  const float* la_ln_b  = (const float*)d_in[19];
  const float* la_Wq    = (const float*)d_in[20];
  const float* la_Wkv   = (const float*)d_in[21];
  const float* la_Wo    = (const float*)d_in[22];
  const float* la_bo    = (const float*)d_in[23];
  const float* lf_ln_g  = (const float*)d_in[24];
  const float* lf_ln_b  = (const float*)d_in[25];
  const float* lf_W1    = (const float*)d_in[26];
  const float* lf_b1    = (const float*)d_in[27];
  const float* lf_W2    = (const float*)d_in[28];
  const float* lf_b2    = (const float*)d_in[29];

  float* ws = (float*)d_ws;
  float* data = ws;                                   // 3,801,088
  float* lat  = ws + 3801088;                         // 1,048,576
  unsigned short* bufA_hi = (unsigned short*)(ws + 4849664); // latn_ca hi|lo
  unsigned short* bufA_lo = bufA_hi + 1048576;
  float* I    = ws + 5898240;
  float* q_l  = I;                                            // 1,048,576 f
  unsigned short* bufB_hi = (unsigned short*)(I + 1048576);   // latn_la hi|lo
  unsigned short* bufB_lo = bufB_hi + 1048576;
  unsigned short* bufC_hi = (unsigned short*)(I + 2097152);   // latn_lf hi|lo
  unsigned short* bufC_lo = bufC_hi + 1048576;
  unsigned short* Kb_l    = (unsigned short*)(I + 3145728);
  unsigned short* Vthi_l  = Kb_l + 1048576;
  unsigned short* Vtlo_l  = Vthi_l + 1048576;
  unsigned short* ao_hi   = (unsigned short*)(I + 4718592);
  unsigned short* ao_lo   = ao_hi + 1048576;
  unsigned short* gg_hi   = (unsigned short*)(I + 8388608);
  float* kv_c = ws + 20578304;                        // 4 x 262,144 z-partials
  unsigned short* Kb_c = (unsigned short*)(ws + 21626880);
  unsigned short* Vt_c = Kb_c + 131072;
  unsigned short* wsp  = (unsigned short*)(ws + 21757952);   // 4 x LSTRIDE

  // ---- everything-prep: l2l + encode + all weight preps, one dispatch ----
  k_prep_all<<<4928, 256, 0, stream>>>(x, W_l2l, b_l2l, latents, lat, data,
      la_Wq, la_Wkv, la_Wo, lf_W1, lf_W2, ca_Wkv, ca_Wq, ca_Wo, cf_W2, cf_W1, cf_b1, wsp);
  // ---- ln_la(0) ----
  k_ln512w<<<512, 256, 0, stream>>>(lat, la_ln_g, la_ln_b, bufB_hi, bufB_lo);

  // ---- software-pipelined layers: latent(i) overlapped with cross(i-1) ----
  for (int i=0;i<5;i++){
    int li = (i<4)? i : 3;
    int lx = (i>0)? i-1 : 0;
    bool L = (i<4), X = (i>0);
    const unsigned short* wlat = wsp + (size_t)li*LSTRIDE;
    const unsigned short* wx   = wsp + (size_t)lx*LSTRIDE;

    int nq = L?192:0, nck = X?64:0;
    k_combo1<<<nq+nck, 256, 0, stream>>>(bufB_hi, wlat, q_l, Kb_l, Vthi_l, Vtlo_l,
                                         bufA_hi, wx+8388608, kv_c, nq);
    int na = L?256:0, nkp = X?256:0;
    k_combo2<<<na+nkp, 256, 0, stream>>>(q_l, Kb_l, Vthi_l, Vtlo_l, ao_hi, ao_lo,
                                         kv_c, Kb_c, Vt_c, na, nkp);
    int nwo = L?128:0, nca = X?2048:0;
    k_combo3<<<nwo+nca, 256, 0, stream>>>(ao_hi, wlat+1572864, la_bo+li*512, lat,
                                          data, ca_ln_q_g+lx*29, ca_ln_q_b+lx*29,
                                          wx+8519680, Kb_c, Vt_c, wx+8521728,
                                          ca_bo+lx*29, nwo);
    int ncf = X?1024:0, nlf = L?512:0;
    k_combo4<<<ncf+nlf, 256, 0, stream>>>(data, cf_ln_g+lx*29, cf_ln_b+lx*29,
                                          wx+8527872, (const float*)(wx+8536064),
                                          wx+8523776, cf_b2+lx*29,
                                          lat, lf_ln_g+li*512, lf_ln_b+li*512,
                                          bufC_hi, bufC_lo, ncf);
    if (L){
      k_mfma_glu<<<dim3(16,32), 256, 0, stream>>>(bufC_hi, wlat+2097152, lf_b1+li*4096,
                                                  gg_hi, gg_hi+4194304);
      k_mfma<<<dim3(16,4,4), 256, 0, stream>>>(gg_hi, wlat+6291456, lf_b2+li*512, lat,
                                               2048, 512, 2048, 4, 1);
      int ln2 = (i<3)? i+1 : 3;
      k_ln512d<<<512, 256, 0, stream>>>(lat,
                                        ca_ln_c_g+li*512, ca_ln_c_b+li*512, bufA_hi, bufA_lo,
                                        la_ln_g+ln2*512, la_ln_b+ln2*512, bufB_hi, bufB_lo);
    }
  }

  k_out<<<1536, 256, 0, stream>>>(data, (float*)d_out);
}